// Round 1
// baseline (656.977 us; speedup 1.0000x reference)
//
#include <hip/hip_runtime.h>
#include <math.h>

#define MAXN_BALL (1.0f - 1e-5f)
#define ART_CLIP  (1.0f - 1e-7f)
#define MAXD 384

__device__ __forceinline__ float atanh_c(float x) {
    x = fminf(x, ART_CLIP);
    return 0.5f * logf((1.0f + x) / (1.0f - x));
}
__device__ __forceinline__ float leaky(float x) { return x > 0.0f ? x : 0.2f * x; }

__device__ __forceinline__ float wred_sum(float v) {
#pragma unroll
    for (int m = 32; m >= 1; m >>= 1) v += __shfl_xor(v, m, 64);
    return v;
}
__device__ __forceinline__ float wred_max(float v) {
#pragma unroll
    for (int m = 32; m >= 1; m >>= 1) v = fmaxf(v, __shfl_xor(v, m, 64));
    return v;
}
// block = 128 threads (2 waves)
__device__ __forceinline__ float bred_sum(float v, float* s) {
    v = wred_sum(v);
    __syncthreads();
    if ((threadIdx.x & 63) == 0) s[threadIdx.x >> 6] = v;
    __syncthreads();
    return s[0] + s[1];
}
__device__ __forceinline__ float bred_max(float v, float* s) {
    v = wred_max(v);
    __syncthreads();
    if ((threadIdx.x & 63) == 0) s[threadIdx.x >> 6] = v;
    __syncthreads();
    return fmaxf(s[0], s[1]);
}
__device__ __forceinline__ float4 bred_sum4(float4 v, float* s) {
    v.x = wred_sum(v.x); v.y = wred_sum(v.y); v.z = wred_sum(v.z); v.w = wred_sum(v.w);
    __syncthreads();
    if ((threadIdx.x & 63) == 0) {
        int w = threadIdx.x >> 6;
        s[w * 4 + 0] = v.x; s[w * 4 + 1] = v.y; s[w * 4 + 2] = v.z; s[w * 4 + 3] = v.w;
    }
    __syncthreads();
    return make_float4(s[0] + s[4], s[1] + s[5], s[2] + s[6], s[3] + s[7]);
}
__device__ __forceinline__ float4 bred_max4(float4 v, float* s) {
    v.x = wred_max(v.x); v.y = wred_max(v.y); v.z = wred_max(v.z); v.w = wred_max(v.w);
    __syncthreads();
    if ((threadIdx.x & 63) == 0) {
        int w = threadIdx.x >> 6;
        s[w * 4 + 0] = v.x; s[w * 4 + 1] = v.y; s[w * 4 + 2] = v.z; s[w * 4 + 3] = v.w;
    }
    __syncthreads();
    return make_float4(fmaxf(s[0], s[4]), fmaxf(s[1], s[5]), fmaxf(s[2], s[6]), fmaxf(s[3], s[7]));
}

// ---------------- GEMM: Y[r][o] = sum_k X[r][k]*W[o][k] (+ bias[o]) ----------------
// 32 rows/block, full 128 cols, K split in 2 chunks of 64. 4x4 microtiles.
__global__ __launch_bounds__(256) void k_gemm(const float* __restrict__ X,
                                              const float* __restrict__ W,
                                              const float* __restrict__ bias,
                                              float* __restrict__ Y, int N) {
    __shared__ float xs[32][128];
    __shared__ float wT[64][132];   // [k][o], padded stride 132
    int t = threadIdx.x;
    int r0 = blockIdx.x * 32;
    for (int idx = t; idx < 32 * 128; idx += 256) {
        int r = idx >> 7, k = idx & 127;
        int gr = r0 + r;
        xs[r][k] = (gr < N) ? X[(size_t)gr * 128 + k] : 0.0f;
    }
    int rg = t >> 5;    // 0..7 -> rows rg*4..rg*4+3
    int cg = t & 31;    // 0..31 -> cols cg*4..cg*4+3
    float acc[4][4] = {};
    for (int kk = 0; kk < 128; kk += 64) {
        __syncthreads();
        for (int idx = t; idx < 128 * 64; idx += 256) {
            int o = idx >> 6;     // 0..127
            int k = idx & 63;     // 0..63
            wT[k][o] = W[(size_t)o * 128 + kk + k];
        }
        __syncthreads();
#pragma unroll 8
        for (int k = 0; k < 64; ++k) {
            float4 wv = *(const float4*)&wT[k][cg * 4];
#pragma unroll
            for (int j = 0; j < 4; ++j) {
                float xj = xs[rg * 4 + j][kk + k];
                acc[j][0] += xj * wv.x; acc[j][1] += xj * wv.y;
                acc[j][2] += xj * wv.z; acc[j][3] += xj * wv.w;
            }
        }
    }
    float4 b4 = make_float4(0.f, 0.f, 0.f, 0.f);
    if (bias) b4 = *(const float4*)&bias[cg * 4];
#pragma unroll
    for (int j = 0; j < 4; ++j) {
        int gr = r0 + rg * 4 + j;
        if (gr < N) {
            float4 o4 = make_float4(acc[j][0] + b4.x, acc[j][1] + b4.y,
                                    acc[j][2] + b4.z, acc[j][3] + b4.w);
            *(float4*)&Y[(size_t)gr * 128 + cg * 4] = o4;
        }
    }
}

// ---------------- Per-node stage: attention scalars + hyperbolic transforms ----------------
// in: xe [N,128], x_h [N,128], xh buffer holds mx on entry (in-place -> xh)
__global__ __launch_bounds__(128) void k_node1(const float* __restrict__ xe,
                                               const float* __restrict__ x_h,
                                               float* __restrict__ xh,
                                               float* __restrict__ lx,
                                               float* __restrict__ ai_g, float* __restrict__ aj_g,
                                               float* __restrict__ hi_g, float* __restrict__ hj_g,
                                               float* __restrict__ x2h,
                                               const float* __restrict__ att_e,
                                               const float* __restrict__ att_h,
                                               const float* __restrict__ b_lin_h, int N) {
    __shared__ float sred[8];
    int i = blockIdx.x, t = threadIdx.x;
    size_t base = (size_t)i * 128 + t;
    int hh = t >> 5, dd = t & 31;

    // Euclidean attention scalars from xe
    float xev = xe[base];
    float pi = xev * att_e[hh * 64 + dd];
    float pj = xev * att_e[hh * 64 + 32 + dd];
#pragma unroll
    for (int m = 1; m <= 16; m <<= 1) { pi += __shfl_xor(pi, m, 64); pj += __shfl_xor(pj, m, 64); }
    if (dd == 0) { ai_g[i * 4 + hh] = pi; aj_g[i * 4 + hh] = pj; }

    // mv = proj(mobius_matvec(W_h, x_h)) using mx (in xh buffer)
    float xv = x_h[base];
    float mxv = xh[base];
    float nx2  = bred_sum(xv * xv, sred);
    float nmx2 = bred_sum(mxv * mxv, sred);
    float nxr = sqrtf(nx2),  nxc = fmaxf(nxr, 1e-15f);
    float nmxr = sqrtf(nmx2), nmxc = fmaxf(nmxr, 1e-15f);
    float tt = tanhf(nmxc / nxc * atanh_c(nxc));
    float mvv = tt / nmxc * mxv;
    float nmv = tt * (nmxr / nmxc);
    if (nmv > MAXN_BALL) { mvv *= MAXN_BALL / nmv; nmv = MAXN_BALL; }

    // hb = proj(expmap0(b_lin_h))
    float bv = b_lin_h[t];
    float nb2 = bred_sum(bv * bv, sred);
    float nbr = sqrtf(nb2), nbc = fmaxf(nbr, 1e-15f);
    float tb = tanhf(nbc);
    float hbv = tb / nbc * bv;
    float nhb = tb * (nbr / nbc);
    if (nhb > MAXN_BALL) { hbv *= MAXN_BALL / nhb; nhb = MAXN_BALL; }

    // xh = proj(mobius_add(mv, hb))
    float xy = bred_sum(mvv * hbv, sred);
    float x2 = nmv * nmv, y2 = nhb * nhb;
    float den = fmaxf(1.f + 2.f * xy + x2 * y2, 1e-15f);
    float resv = ((1.f + 2.f * xy + y2) * mvv + (1.f - x2) * hbv) / den;
    float nr2 = bred_sum(resv * resv, sred);
    float nrr = sqrtf(nr2);
    if (nrr > MAXN_BALL) { resv *= MAXN_BALL / nrr; nrr = MAXN_BALL; }
    xh[base] = resv;
    if (t == 0) x2h[i] = nrr * nrr;

    // lx = logmap0(xh)
    float nnc = fmaxf(nrr, 1e-15f);
    float lxv = atanh_c(nnc) / nnc * resv;
    lx[base] = lxv;

    float qi = lxv * att_h[hh * 64 + dd];
    float qj = lxv * att_h[hh * 64 + 32 + dd];
#pragma unroll
    for (int m = 1; m <= 16; m <<= 1) { qi += __shfl_xor(qi, m, 64); qj += __shfl_xor(qj, m, 64); }
    if (dd == 0) { hi_g[i * 4 + hh] = qi; hj_g[i * 4 + hh] = qj; }
}

// ---------------- CSR build ----------------
__global__ void k_histo(const int* __restrict__ ei, int* __restrict__ counts, int E, int N) {
    int idx = blockIdx.x * blockDim.x + threadIdx.x;
    if (idx >= E + N) return;
    int d = (idx < E) ? ei[E + idx] : (idx - E);
    atomicAdd(&counts[d], 1);
}
__global__ __launch_bounds__(256) void k_scan_partial(const int* __restrict__ counts,
                                                      int* __restrict__ bsums, int N) {
    __shared__ int sw[4];
    int s = 0;
    int base = blockIdx.x * 1024;
    for (int j = threadIdx.x; j < 1024; j += 256) {
        int idx = base + j;
        if (idx < N) s += counts[idx];
    }
#pragma unroll
    for (int m = 32; m >= 1; m >>= 1) s += __shfl_xor(s, m, 64);
    if ((threadIdx.x & 63) == 0) sw[threadIdx.x >> 6] = s;
    __syncthreads();
    if (threadIdx.x == 0) bsums[blockIdx.x] = sw[0] + sw[1] + sw[2] + sw[3];
}
__global__ __launch_bounds__(256) void k_scan_bsums(int* __restrict__ bsums, int nb,
                                                    int* __restrict__ rowptr, int N) {
    __shared__ int ss[256];
    int t = threadIdx.x;
    int v = (t < nb) ? bsums[t] : 0;
    ss[t] = v; __syncthreads();
    for (int off = 1; off < 256; off <<= 1) {
        int u = (t >= off) ? ss[t - off] : 0;
        __syncthreads();
        ss[t] += u;
        __syncthreads();
    }
    if (t < nb) bsums[t] = ss[t] - v;   // exclusive
    if (t == 255) rowptr[N] = ss[255];
}
__global__ __launch_bounds__(256) void k_scan_final(const int* __restrict__ counts,
                                                    const int* __restrict__ bsums,
                                                    int* __restrict__ rowptr, int N) {
    __shared__ int ss[256];
    int t = threadIdx.x;
    int base = blockIdx.x * 1024 + t * 4;
    int v0 = (base + 0 < N) ? counts[base + 0] : 0;
    int v1 = (base + 1 < N) ? counts[base + 1] : 0;
    int v2 = (base + 2 < N) ? counts[base + 2] : 0;
    int v3 = (base + 3 < N) ? counts[base + 3] : 0;
    int tot = v0 + v1 + v2 + v3;
    ss[t] = tot; __syncthreads();
    for (int off = 1; off < 256; off <<= 1) {
        int u = (t >= off) ? ss[t - off] : 0;
        __syncthreads();
        ss[t] += u;
        __syncthreads();
    }
    int excl = ss[t] - tot + bsums[blockIdx.x];
    if (base + 0 < N) rowptr[base + 0] = excl;
    if (base + 1 < N) rowptr[base + 1] = excl + v0;
    if (base + 2 < N) rowptr[base + 2] = excl + v0 + v1;
    if (base + 3 < N) rowptr[base + 3] = excl + v0 + v1 + v2;
}
__global__ void k_scatter(const int* __restrict__ ei, const int* __restrict__ rowptr,
                          int* __restrict__ cursor, int* __restrict__ srcs, int E, int N) {
    int idx = blockIdx.x * blockDim.x + threadIdx.x;
    if (idx >= E + N) return;
    int s, d;
    if (idx < E) { s = ei[idx]; d = ei[E + idx]; } else { s = d = idx - E; }
    int p = rowptr[d] + atomicAdd(&cursor[d], 1);
    srcs[p] = s;
}

// ---------------- Final per-node kernel: distances, 3 softmaxes, aggregation, fusion ----------------
__global__ __launch_bounds__(128) void k_node_final(
    const float* __restrict__ xh, const float* __restrict__ x2h,
    const float* __restrict__ lx, const float* __restrict__ xe,
    const float* __restrict__ hi_g, const float* __restrict__ hj_g,
    const float* __restrict__ ai_g, const float* __restrict__ aj_g,
    const int* __restrict__ rowptr, const int* __restrict__ srcs,
    const float* __restrict__ b_e, const float* __restrict__ b_h,
    const float* __restrict__ att_hf, const float* __restrict__ att_ef,
    float* __restrict__ out, int N) {
    __shared__ float sxh[128];
    __shared__ int   s_src[MAXD];
    __shared__ float s_d[MAXD];
    __shared__ float s_ah[MAXD * 4];
    __shared__ float s_ae[MAXD * 4];
    __shared__ float sred[8];

    int i = blockIdx.x;
    int t = threadIdx.x;
    int w = t >> 6, l = t & 63;
    int rs = rowptr[i];
    int deg = rowptr[i + 1] - rs;
    if (deg > MAXD) deg = MAXD;

    sxh[t] = xh[(size_t)i * 128 + t];
    for (int e = t; e < deg; e += 128) s_src[e] = srcs[rs + e];
    __syncthreads();

    float x2i = x2h[i];
    // Phase A: hyperbolic distance per edge (one wave per edge)
    for (int e = w; e < deg; e += 2) {
        int j = s_src[e];
        const float* xj = &xh[(size_t)j * 128];
        float p = xj[l] * sxh[l] + xj[64 + l] * sxh[64 + l];
        float y2 = x2h[j];
        p = wred_sum(p);
        if (l == 0) {
            float xy = p;
            float A = 1.f - 2.f * xy + y2;
            float B = 1.f - x2i;
            float den = fmaxf(1.f - 2.f * xy + x2i * y2, 1e-15f);
            float num2 = fmaxf(A * A * x2i - 2.f * A * B * xy + B * B * y2, 0.f);
            float nma = fminf(sqrtf(num2) / den, ART_CLIP);
            s_d[e] = logf((1.f + nma) / (1.f - nma));  // 2*artanh(nma)
        }
    }
    __syncthreads();

    // Phase B: softmax over distances
    float lm = -INFINITY;
    for (int e = t; e < deg; e += 128) lm = fmaxf(lm, s_d[e]);
    float md = bred_max(lm, sred);
    float lsum = 0.f;
    for (int e = t; e < deg; e += 128) { float ex = expf(s_d[e] - md); s_d[e] = ex; lsum += ex; }
    float sd = bred_sum(lsum, sred);
    float dinv = 1.f / (sd + 1e-16f);

    // Phase C: per-edge per-head logits + softmaxes
    float4 hi4 = *(const float4*)&hi_g[i * 4];
    float4 ai4 = *(const float4*)&ai_g[i * 4];
    float4 mh = make_float4(-INFINITY, -INFINITY, -INFINITY, -INFINITY);
    float4 me = mh;
    for (int e = t; e < deg; e += 128) {
        int j = s_src[e];
        float ds = s_d[e] * dinv;
        float4 hj4 = *(const float4*)&hj_g[j * 4];
        float4 aj4 = *(const float4*)&aj_g[j * 4];
        float4 vh, ve;
        vh.x = leaky((hi4.x + hj4.x) * ds); vh.y = leaky((hi4.y + hj4.y) * ds);
        vh.z = leaky((hi4.z + hj4.z) * ds); vh.w = leaky((hi4.w + hj4.w) * ds);
        ve.x = leaky(ai4.x + aj4.x); ve.y = leaky(ai4.y + aj4.y);
        ve.z = leaky(ai4.z + aj4.z); ve.w = leaky(ai4.w + aj4.w);
        *(float4*)&s_ah[e * 4] = vh;
        *(float4*)&s_ae[e * 4] = ve;
        mh.x = fmaxf(mh.x, vh.x); mh.y = fmaxf(mh.y, vh.y); mh.z = fmaxf(mh.z, vh.z); mh.w = fmaxf(mh.w, vh.w);
        me.x = fmaxf(me.x, ve.x); me.y = fmaxf(me.y, ve.y); me.z = fmaxf(me.z, ve.z); me.w = fmaxf(me.w, ve.w);
    }
    mh = bred_max4(mh, sred);
    me = bred_max4(me, sred);
    float4 sh = make_float4(0.f, 0.f, 0.f, 0.f), se = sh;
    for (int e = t; e < deg; e += 128) {
        float4 vh = *(float4*)&s_ah[e * 4];
        float4 ve = *(float4*)&s_ae[e * 4];
        vh.x = expf(vh.x - mh.x); vh.y = expf(vh.y - mh.y); vh.z = expf(vh.z - mh.z); vh.w = expf(vh.w - mh.w);
        ve.x = expf(ve.x - me.x); ve.y = expf(ve.y - me.y); ve.z = expf(ve.z - me.z); ve.w = expf(ve.w - me.w);
        *(float4*)&s_ah[e * 4] = vh;
        *(float4*)&s_ae[e * 4] = ve;
        sh.x += vh.x; sh.y += vh.y; sh.z += vh.z; sh.w += vh.w;
        se.x += ve.x; se.y += ve.y; se.z += ve.z; se.w += ve.w;
    }
    sh = bred_sum4(sh, sred);
    se = bred_sum4(se, sred);
    __syncthreads();

    // Phase D: aggregation (all threads walk all edges; thread t = output dim)
    int ht = t >> 5;
    float shh = (ht == 0) ? sh.x : (ht == 1) ? sh.y : (ht == 2) ? sh.z : sh.w;
    float seh = (ht == 0) ? se.x : (ht == 1) ? se.y : (ht == 2) ? se.z : se.w;
    float rhinv = 1.f / (shh + 1e-16f);
    float reinv = 1.f / (seh + 1e-16f);
    float acc_e = 0.f, acc_h = 0.f;
    for (int e = 0; e < deg; ++e) {
        int j = s_src[e];
        float ae = s_ae[e * 4 + ht] * reinv;
        float ah = s_ah[e * 4 + ht] * rhinv;
        acc_e += ae * xe[(size_t)j * 128 + t];
        acc_h += ah * lx[(size_t)j * 128 + t];
    }

    // Phase E: epilogue
    float e_out = fmaxf(acc_e + b_e[t], 0.f);
    float o_t   = fmaxf(acc_h + b_h[t], 0.f);
    // h_out = proj(expmap0(o_t))
    float n2 = bred_sum(o_t * o_t, sred);
    float n_raw = sqrtf(n2), n_c = fmaxf(n_raw, 1e-15f);
    float th = tanhf(n_c);
    float h_out = th / n_c * o_t;
    float nh = th * (n_raw / n_c);
    if (nh > MAXN_BALL) { h_out *= MAXN_BALL / nh; nh = MAXN_BALL; }
    // ye = proj(expmap0(e_out))
    float ne2 = bred_sum(e_out * e_out, sred);
    float nE_raw = sqrtf(ne2), nE_c = fmaxf(nE_raw, 1e-15f);
    float tE = tanhf(nE_c);
    float ye = tE / nE_c * e_out;
    float ny = tE * (nE_raw / nE_c);
    if (ny > MAXN_BALL) { ye *= MAXN_BALL / ny; ny = MAXN_BALL; }
    // dist_f = pdist(h_out, ye) * att_hf
    float xyv = bred_sum(h_out * ye, sred);
    float x2f = nh * nh, y2f = ny * ny;
    float A = 1.f - 2.f * xyv + y2f, B = 1.f - x2f;
    float den = fmaxf(1.f - 2.f * xyv + x2f * y2f, 1e-15f);
    float num2 = fmaxf(A * A * x2f - 2.f * A * B * xyv + B * B * y2f, 0.f);
    float nma = fminf(sqrtf(num2) / den, ART_CLIP);
    float distf = logf((1.f + nma) / (1.f - nma)) * att_hf[0];
    // xe2 = proj(mobius_scalar_mul(distf, ye)) ; track as scalar multiple of ye
    float nyc = fmaxf(ny, 1e-15f);
    float s1 = tanhf(distf * atanh_c(nyc)) / nyc;
    float nxe2 = fabsf(s1) * ny;
    if (nxe2 > MAXN_BALL) { s1 *= MAXN_BALL / nxe2; nxe2 = MAXN_BALL; }
    float xe2 = s1 * ye;
    float xy2 = s1 * xyv;       // h_out . xe2 (exact: xe2 = s1*ye)
    float y22 = nxe2 * nxe2;
    // h_fused = proj(mobius_add(h_out, xe2))
    float den2 = fmaxf(1.f + 2.f * xy2 + x2f * y22, 1e-15f);
    float hf = ((1.f + 2.f * xy2 + y22) * h_out + (1.f - x2f) * xe2) / den2;
    float nf2 = bred_sum(hf * hf, sred);
    float nf = sqrtf(nf2);
    if (nf > MAXN_BALL) hf *= MAXN_BALL / nf;
    out[(size_t)i * 128 + t] = hf;
    // EFusion
    float nhc = fmaxf(nh, 1e-15f);
    float lh = atanh_c(nhc) / nhc * h_out;
    float diff = lh - e_out;
    float de2 = bred_sum(diff * diff, sred);
    float de = de2 * att_ef[0];
    out[(size_t)N * 128 + (size_t)i * 128 + t] = e_out + de * lh;
}

extern "C" void kernel_launch(void* const* d_in, const int* in_sizes, int n_in,
                              void* d_out, int out_size, void* d_ws, size_t ws_size,
                              hipStream_t stream) {
    const float* x_e      = (const float*)d_in[0];
    const float* x_h      = (const float*)d_in[1];
    const int*   ei       = (const int*)d_in[2];
    const float* W_e      = (const float*)d_in[3];
    const float* b_lin_e  = (const float*)d_in[4];
    const float* att_e    = (const float*)d_in[5];
    const float* b_e      = (const float*)d_in[6];
    const float* W_h      = (const float*)d_in[7];
    const float* b_lin_h  = (const float*)d_in[8];
    const float* att_h    = (const float*)d_in[9];
    const float* b_h      = (const float*)d_in[10];
    const float* att_hf   = (const float*)d_in[11];
    const float* att_ef   = (const float*)d_in[12];

    int N = in_sizes[0] / 128;
    int E = in_sizes[2] / 2;
    int EN = E + N;

    char* ws = (char*)d_ws;
    size_t off = 0;
    auto alloc = [&](size_t bytes) -> void* {
        void* p = ws + off;
        off = (off + bytes + 255) & ~(size_t)255;
        return p;
    };
    float* xe    = (float*)alloc((size_t)N * 128 * 4);
    float* xh    = (float*)alloc((size_t)N * 128 * 4);  // mx then xh (in place)
    float* lx    = (float*)alloc((size_t)N * 128 * 4);
    float* ai_g  = (float*)alloc((size_t)N * 4 * 4);
    float* aj_g  = (float*)alloc((size_t)N * 4 * 4);
    float* hi_g  = (float*)alloc((size_t)N * 4 * 4);
    float* hj_g  = (float*)alloc((size_t)N * 4 * 4);
    float* x2h   = (float*)alloc((size_t)N * 4);
    int*   counts= (int*)alloc((size_t)N * 4);
    int*   rowptr= (int*)alloc((size_t)(N + 1) * 4);
    int*   bsums = (int*)alloc(256 * 4);
    int*   srcs  = (int*)alloc((size_t)EN * 4);

    hipMemsetAsync(counts, 0, (size_t)N * 4, stream);

    int gblocks = (N + 31) / 32;
    k_gemm<<<gblocks, 256, 0, stream>>>(x_e, W_e, b_lin_e, xe, N);
    k_gemm<<<gblocks, 256, 0, stream>>>(x_h, W_h, nullptr, xh, N);
    k_node1<<<N, 128, 0, stream>>>(xe, x_h, xh, lx, ai_g, aj_g, hi_g, hj_g, x2h,
                                   att_e, att_h, b_lin_h, N);

    int eblocks = (EN + 255) / 256;
    k_histo<<<eblocks, 256, 0, stream>>>(ei, counts, E, N);
    int nb = (N + 1023) / 1024;
    k_scan_partial<<<nb, 256, 0, stream>>>(counts, bsums, N);
    k_scan_bsums<<<1, 256, 0, stream>>>(bsums, nb, rowptr, N);
    k_scan_final<<<nb, 256, 0, stream>>>(counts, bsums, rowptr, N);
    hipMemsetAsync(counts, 0, (size_t)N * 4, stream);
    k_scatter<<<eblocks, 256, 0, stream>>>(ei, rowptr, counts, srcs, E, N);

    k_node_final<<<N, 128, 0, stream>>>(xh, x2h, lx, xe, hi_g, hj_g, ai_g, aj_g,
                                        rowptr, srcs, b_e, b_h, att_hf, att_ef,
                                        (float*)d_out, N);
}

// Round 2
// 544.012 us; speedup vs baseline: 1.2077x; 1.2077x over previous
//
#include <hip/hip_runtime.h>
#include <math.h>

#define MAXN_BALL (1.0f - 1e-5f)
#define ART_CLIP  (1.0f - 1e-7f)
#define MAXD 128   // max supported in-degree (incl. self-loop); Poisson(10) => P(>128) ~ 0

__device__ __forceinline__ float atanh_c(float x) {
    x = fminf(x, ART_CLIP);
    return 0.5f * logf((1.0f + x) / (1.0f - x));
}
__device__ __forceinline__ float leaky(float x) { return x > 0.0f ? x : 0.2f * x; }

__device__ __forceinline__ float wred_sum(float v) {
#pragma unroll
    for (int m = 32; m >= 1; m >>= 1) v += __shfl_xor(v, m, 64);
    return v;
}
__device__ __forceinline__ float wred_max(float v) {
#pragma unroll
    for (int m = 32; m >= 1; m >>= 1) v = fmaxf(v, __shfl_xor(v, m, 64));
    return v;
}
// block = 128 threads (2 waves)
__device__ __forceinline__ float bred_sum(float v, float* s) {
    v = wred_sum(v);
    __syncthreads();
    if ((threadIdx.x & 63) == 0) s[threadIdx.x >> 6] = v;
    __syncthreads();
    return s[0] + s[1];
}
__device__ __forceinline__ float bred_max(float v, float* s) {
    v = wred_max(v);
    __syncthreads();
    if ((threadIdx.x & 63) == 0) s[threadIdx.x >> 6] = v;
    __syncthreads();
    return fmaxf(s[0], s[1]);
}
__device__ __forceinline__ float4 bred_sum4(float4 v, float* s) {
    v.x = wred_sum(v.x); v.y = wred_sum(v.y); v.z = wred_sum(v.z); v.w = wred_sum(v.w);
    __syncthreads();
    if ((threadIdx.x & 63) == 0) {
        int w = threadIdx.x >> 6;
        s[w * 4 + 0] = v.x; s[w * 4 + 1] = v.y; s[w * 4 + 2] = v.z; s[w * 4 + 3] = v.w;
    }
    __syncthreads();
    return make_float4(s[0] + s[4], s[1] + s[5], s[2] + s[6], s[3] + s[7]);
}
__device__ __forceinline__ float4 bred_max4(float4 v, float* s) {
    v.x = wred_max(v.x); v.y = wred_max(v.y); v.z = wred_max(v.z); v.w = wred_max(v.w);
    __syncthreads();
    if ((threadIdx.x & 63) == 0) {
        int w = threadIdx.x >> 6;
        s[w * 4 + 0] = v.x; s[w * 4 + 1] = v.y; s[w * 4 + 2] = v.z; s[w * 4 + 3] = v.w;
    }
    __syncthreads();
    return make_float4(fmaxf(s[0], s[4]), fmaxf(s[1], s[5]), fmaxf(s[2], s[6]), fmaxf(s[3], s[7]));
}

// ---------------- GEMM: Y[r][o] = sum_k X[r][k]*W[o][k] (+ bias[o]) ----------------
__global__ __launch_bounds__(256) void k_gemm(const float* __restrict__ X,
                                              const float* __restrict__ W,
                                              const float* __restrict__ bias,
                                              float* __restrict__ Y, int N) {
    __shared__ float xs[32][128];
    __shared__ float wT[64][132];   // [k][o], padded stride 132
    int t = threadIdx.x;
    int r0 = blockIdx.x * 32;
    for (int idx = t; idx < 32 * 128; idx += 256) {
        int r = idx >> 7, k = idx & 127;
        int gr = r0 + r;
        xs[r][k] = (gr < N) ? X[(size_t)gr * 128 + k] : 0.0f;
    }
    int rg = t >> 5;    // 0..7 -> rows rg*4..rg*4+3
    int cg = t & 31;    // 0..31 -> cols cg*4..cg*4+3
    float acc[4][4] = {};
    for (int kk = 0; kk < 128; kk += 64) {
        __syncthreads();
        for (int idx = t; idx < 128 * 64; idx += 256) {
            int o = idx >> 6;
            int k = idx & 63;
            wT[k][o] = W[(size_t)o * 128 + kk + k];
        }
        __syncthreads();
#pragma unroll 8
        for (int k = 0; k < 64; ++k) {
            float4 wv = *(const float4*)&wT[k][cg * 4];
#pragma unroll
            for (int j = 0; j < 4; ++j) {
                float xj = xs[rg * 4 + j][kk + k];
                acc[j][0] += xj * wv.x; acc[j][1] += xj * wv.y;
                acc[j][2] += xj * wv.z; acc[j][3] += xj * wv.w;
            }
        }
    }
    float4 b4 = make_float4(0.f, 0.f, 0.f, 0.f);
    if (bias) b4 = *(const float4*)&bias[cg * 4];
#pragma unroll
    for (int j = 0; j < 4; ++j) {
        int gr = r0 + rg * 4 + j;
        if (gr < N) {
            float4 o4 = make_float4(acc[j][0] + b4.x, acc[j][1] + b4.y,
                                    acc[j][2] + b4.z, acc[j][3] + b4.w);
            *(float4*)&Y[(size_t)gr * 128 + cg * 4] = o4;
        }
    }
}

// ---------------- Per-node stage ----------------
// xh buffer holds mx on entry (in-place -> xh). Writes lam[i]=artanh(|xh|)/|xh| instead of lx rows.
__global__ __launch_bounds__(128) void k_node1(const float* __restrict__ xe,
                                               const float* __restrict__ x_h,
                                               float* __restrict__ xh,
                                               float* __restrict__ lam_g,
                                               float* __restrict__ ai_g, float* __restrict__ aj_g,
                                               float* __restrict__ hi_g, float* __restrict__ hj_g,
                                               float* __restrict__ x2h,
                                               const float* __restrict__ att_e,
                                               const float* __restrict__ att_h,
                                               const float* __restrict__ b_lin_h, int N) {
    __shared__ float sred[8];
    int i = blockIdx.x, t = threadIdx.x;
    size_t base = (size_t)i * 128 + t;
    int hh = t >> 5, dd = t & 31;

    // Euclidean attention scalars
    float xev = xe[base];
    float pi = xev * att_e[hh * 64 + dd];
    float pj = xev * att_e[hh * 64 + 32 + dd];
#pragma unroll
    for (int m = 1; m <= 16; m <<= 1) { pi += __shfl_xor(pi, m, 64); pj += __shfl_xor(pj, m, 64); }
    if (dd == 0) { ai_g[i * 4 + hh] = pi; aj_g[i * 4 + hh] = pj; }

    // mv = proj(mobius_matvec(W_h, x_h))
    float xv = x_h[base];
    float mxv = xh[base];
    float nx2  = bred_sum(xv * xv, sred);
    float nmx2 = bred_sum(mxv * mxv, sred);
    float nxr = sqrtf(nx2),  nxc = fmaxf(nxr, 1e-15f);
    float nmxr = sqrtf(nmx2), nmxc = fmaxf(nmxr, 1e-15f);
    float tt = tanhf(nmxc / nxc * atanh_c(nxc));
    float mvv = tt / nmxc * mxv;
    float nmv = tt * (nmxr / nmxc);
    if (nmv > MAXN_BALL) { mvv *= MAXN_BALL / nmv; nmv = MAXN_BALL; }

    // hb = proj(expmap0(b_lin_h))
    float bv = b_lin_h[t];
    float nb2 = bred_sum(bv * bv, sred);
    float nbr = sqrtf(nb2), nbc = fmaxf(nbr, 1e-15f);
    float tb = tanhf(nbc);
    float hbv = tb / nbc * bv;
    float nhb = tb * (nbr / nbc);
    if (nhb > MAXN_BALL) { hbv *= MAXN_BALL / nhb; nhb = MAXN_BALL; }

    // xh = proj(mobius_add(mv, hb))
    float xy = bred_sum(mvv * hbv, sred);
    float x2 = nmv * nmv, y2 = nhb * nhb;
    float den = fmaxf(1.f + 2.f * xy + x2 * y2, 1e-15f);
    float resv = ((1.f + 2.f * xy + y2) * mvv + (1.f - x2) * hbv) / den;
    float nr2 = bred_sum(resv * resv, sred);
    float nrr = sqrtf(nr2);
    if (nrr > MAXN_BALL) { resv *= MAXN_BALL / nrr; nrr = MAXN_BALL; }
    xh[base] = resv;
    if (t == 0) x2h[i] = nrr * nrr;

    // lam = artanh(n)/n  (lx = lam * xh)
    float nnc = fmaxf(nrr, 1e-15f);
    float lam = atanh_c(nnc) / nnc;
    if (t == 0) lam_g[i] = lam;
    float lxv = lam * resv;

    float qi = lxv * att_h[hh * 64 + dd];
    float qj = lxv * att_h[hh * 64 + 32 + dd];
#pragma unroll
    for (int m = 1; m <= 16; m <<= 1) { qi += __shfl_xor(qi, m, 64); qj += __shfl_xor(qj, m, 64); }
    if (dd == 0) { hi_g[i * 4 + hh] = qi; hj_g[i * 4 + hh] = qj; }
}

// ---------------- CSR build ----------------
__global__ void k_histo(const int* __restrict__ ei, int* __restrict__ counts, int E, int N) {
    int idx = blockIdx.x * blockDim.x + threadIdx.x;
    if (idx >= E + N) return;
    int d = (idx < E) ? ei[E + idx] : (idx - E);
    atomicAdd(&counts[d], 1);
}
__global__ __launch_bounds__(256) void k_scan_partial(const int* __restrict__ counts,
                                                      int* __restrict__ bsums, int N) {
    __shared__ int sw[4];
    int s = 0;
    int base = blockIdx.x * 1024;
    for (int j = threadIdx.x; j < 1024; j += 256) {
        int idx = base + j;
        if (idx < N) s += counts[idx];
    }
#pragma unroll
    for (int m = 32; m >= 1; m >>= 1) s += __shfl_xor(s, m, 64);
    if ((threadIdx.x & 63) == 0) sw[threadIdx.x >> 6] = s;
    __syncthreads();
    if (threadIdx.x == 0) bsums[blockIdx.x] = sw[0] + sw[1] + sw[2] + sw[3];
}
__global__ __launch_bounds__(256) void k_scan_bsums(int* __restrict__ bsums, int nb,
                                                    int* __restrict__ rowptr, int N) {
    __shared__ int ss[256];
    int t = threadIdx.x;
    int v = (t < nb) ? bsums[t] : 0;
    ss[t] = v; __syncthreads();
    for (int off = 1; off < 256; off <<= 1) {
        int u = (t >= off) ? ss[t - off] : 0;
        __syncthreads();
        ss[t] += u;
        __syncthreads();
    }
    if (t < nb) bsums[t] = ss[t] - v;
    if (t == 255) rowptr[N] = ss[255];
}
__global__ __launch_bounds__(256) void k_scan_final(const int* __restrict__ counts,
                                                    const int* __restrict__ bsums,
                                                    int* __restrict__ rowptr, int N) {
    __shared__ int ss[256];
    int t = threadIdx.x;
    int base = blockIdx.x * 1024 + t * 4;
    int v0 = (base + 0 < N) ? counts[base + 0] : 0;
    int v1 = (base + 1 < N) ? counts[base + 1] : 0;
    int v2 = (base + 2 < N) ? counts[base + 2] : 0;
    int v3 = (base + 3 < N) ? counts[base + 3] : 0;
    int tot = v0 + v1 + v2 + v3;
    ss[t] = tot; __syncthreads();
    for (int off = 1; off < 256; off <<= 1) {
        int u = (t >= off) ? ss[t - off] : 0;
        __syncthreads();
        ss[t] += u;
        __syncthreads();
    }
    int excl = ss[t] - tot + bsums[blockIdx.x];
    if (base + 0 < N) rowptr[base + 0] = excl;
    if (base + 1 < N) rowptr[base + 1] = excl + v0;
    if (base + 2 < N) rowptr[base + 2] = excl + v0 + v1;
    if (base + 3 < N) rowptr[base + 3] = excl + v0 + v1 + v2;
}
__global__ void k_scatter(const int* __restrict__ ei, const int* __restrict__ rowptr,
                          int* __restrict__ cursor, int* __restrict__ srcs, int E, int N) {
    int idx = blockIdx.x * blockDim.x + threadIdx.x;
    if (idx >= E + N) return;
    int s, d;
    if (idx < E) { s = ei[idx]; d = ei[E + idx]; } else { s = d = idx - E; }
    int p = rowptr[d] + atomicAdd(&cursor[d], 1);
    srcs[p] = s;
}

// ---------------- Final per-node kernel ----------------
__global__ __launch_bounds__(128) void k_node_final(
    const float* __restrict__ xh, const float* __restrict__ x2h,
    const float* __restrict__ lam_g, const float* __restrict__ xe,
    const float* __restrict__ hi_g, const float* __restrict__ hj_g,
    const float* __restrict__ ai_g, const float* __restrict__ aj_g,
    const int* __restrict__ rowptr, const int* __restrict__ srcs,
    const float* __restrict__ b_e, const float* __restrict__ b_h,
    const float* __restrict__ att_hf, const float* __restrict__ att_ef,
    float* __restrict__ out, int N) {
    __shared__ float sxh[128];
    __shared__ int   s_src[MAXD];
    __shared__ float s_d[MAXD];
    __shared__ float s_ah[MAXD * 4];
    __shared__ float s_ae[MAXD * 4];
    __shared__ float s_accE[2][128];
    __shared__ float s_accH[2][128];
    __shared__ float sred[8];

    int i = blockIdx.x;
    int t = threadIdx.x;
    int w = t >> 6, l = t & 63;
    int rs = rowptr[i];
    int deg = rowptr[i + 1] - rs;
    if (deg > MAXD) deg = MAXD;

    sxh[t] = xh[(size_t)i * 128 + t];
    for (int e = t; e < deg; e += 128) s_src[e] = srcs[rs + e];
    __syncthreads();

    float x2i = x2h[i];
    float2 sx2 = *(const float2*)&sxh[2 * l];   // this lane's pair of dims of xh[i]

    // Phase A: hyperbolic distance per edge (wave per edge, unrolled x2, float2 loads)
    {
        int e = w;
        for (; e + 2 < deg; e += 4) {
            int j0 = s_src[e], j1 = s_src[e + 2];
            float2 a0 = *(const float2*)&xh[(size_t)j0 * 128 + 2 * l];
            float2 a1 = *(const float2*)&xh[(size_t)j1 * 128 + 2 * l];
            float y20 = x2h[j0], y21 = x2h[j1];
            float p0 = a0.x * sx2.x + a0.y * sx2.y;
            float p1 = a1.x * sx2.x + a1.y * sx2.y;
#pragma unroll
            for (int m = 32; m >= 1; m >>= 1) {
                p0 += __shfl_xor(p0, m, 64);
                p1 += __shfl_xor(p1, m, 64);
            }
            if (l == 0) {
                {
                    float xy = p0;
                    float A = 1.f - 2.f * xy + y20;
                    float B = 1.f - x2i;
                    float den = fmaxf(1.f - 2.f * xy + x2i * y20, 1e-15f);
                    float num2 = fmaxf(A * A * x2i - 2.f * A * B * xy + B * B * y20, 0.f);
                    float nma = fminf(sqrtf(num2) / den, ART_CLIP);
                    s_d[e] = logf((1.f + nma) / (1.f - nma));
                }
                {
                    float xy = p1;
                    float A = 1.f - 2.f * xy + y21;
                    float B = 1.f - x2i;
                    float den = fmaxf(1.f - 2.f * xy + x2i * y21, 1e-15f);
                    float num2 = fmaxf(A * A * x2i - 2.f * A * B * xy + B * B * y21, 0.f);
                    float nma = fminf(sqrtf(num2) / den, ART_CLIP);
                    s_d[e + 2] = logf((1.f + nma) / (1.f - nma));
                }
            }
        }
        for (; e < deg; e += 2) {
            int j = s_src[e];
            float2 a = *(const float2*)&xh[(size_t)j * 128 + 2 * l];
            float y2 = x2h[j];
            float p = a.x * sx2.x + a.y * sx2.y;
            p = wred_sum(p);
            if (l == 0) {
                float xy = p;
                float A = 1.f - 2.f * xy + y2;
                float B = 1.f - x2i;
                float den = fmaxf(1.f - 2.f * xy + x2i * y2, 1e-15f);
                float num2 = fmaxf(A * A * x2i - 2.f * A * B * xy + B * B * y2, 0.f);
                float nma = fminf(sqrtf(num2) / den, ART_CLIP);
                s_d[e] = logf((1.f + nma) / (1.f - nma));
            }
        }
    }
    __syncthreads();

    // Phase B: softmax over distances
    float lm = -INFINITY;
    for (int e = t; e < deg; e += 128) lm = fmaxf(lm, s_d[e]);
    float md = bred_max(lm, sred);
    float lsum = 0.f;
    for (int e = t; e < deg; e += 128) { float ex = expf(s_d[e] - md); s_d[e] = ex; lsum += ex; }
    float sd = bred_sum(lsum, sred);
    float dinv = 1.f / (sd + 1e-16f);

    // Phase C: per-edge per-head logits + softmaxes (lam folded into s_ah post-exp)
    float4 hi4 = *(const float4*)&hi_g[i * 4];
    float4 ai4 = *(const float4*)&ai_g[i * 4];
    float4 mh = make_float4(-INFINITY, -INFINITY, -INFINITY, -INFINITY);
    float4 me = mh;
    for (int e = t; e < deg; e += 128) {
        int j = s_src[e];
        float ds = s_d[e] * dinv;
        float4 hj4 = *(const float4*)&hj_g[j * 4];
        float4 aj4 = *(const float4*)&aj_g[j * 4];
        float4 vh, ve;
        vh.x = leaky((hi4.x + hj4.x) * ds); vh.y = leaky((hi4.y + hj4.y) * ds);
        vh.z = leaky((hi4.z + hj4.z) * ds); vh.w = leaky((hi4.w + hj4.w) * ds);
        ve.x = leaky(ai4.x + aj4.x); ve.y = leaky(ai4.y + aj4.y);
        ve.z = leaky(ai4.z + aj4.z); ve.w = leaky(ai4.w + aj4.w);
        *(float4*)&s_ah[e * 4] = vh;
        *(float4*)&s_ae[e * 4] = ve;
        mh.x = fmaxf(mh.x, vh.x); mh.y = fmaxf(mh.y, vh.y); mh.z = fmaxf(mh.z, vh.z); mh.w = fmaxf(mh.w, vh.w);
        me.x = fmaxf(me.x, ve.x); me.y = fmaxf(me.y, ve.y); me.z = fmaxf(me.z, ve.z); me.w = fmaxf(me.w, ve.w);
    }
    mh = bred_max4(mh, sred);
    me = bred_max4(me, sred);
    float4 sh = make_float4(0.f, 0.f, 0.f, 0.f), se = sh;
    for (int e = t; e < deg; e += 128) {
        int j = s_src[e];
        float lamj = lam_g[j];
        float4 vh = *(float4*)&s_ah[e * 4];
        float4 ve = *(float4*)&s_ae[e * 4];
        vh.x = expf(vh.x - mh.x); vh.y = expf(vh.y - mh.y); vh.z = expf(vh.z - mh.z); vh.w = expf(vh.w - mh.w);
        ve.x = expf(ve.x - me.x); ve.y = expf(ve.y - me.y); ve.z = expf(ve.z - me.z); ve.w = expf(ve.w - me.w);
        sh.x += vh.x; sh.y += vh.y; sh.z += vh.z; sh.w += vh.w;
        se.x += ve.x; se.y += ve.y; se.z += ve.z; se.w += ve.w;
        // fold lam_j into hyperbolic weights: aggregated vector is lx[j] = lam_j*xh[j]
        vh.x *= lamj; vh.y *= lamj; vh.z *= lamj; vh.w *= lamj;
        *(float4*)&s_ah[e * 4] = vh;
        *(float4*)&s_ae[e * 4] = ve;
    }
    sh = bred_sum4(sh, sred);
    se = bred_sum4(se, sred);
    __syncthreads();

    // Phase D: aggregation. Waves split edges; lane l covers dims {2l, 2l+1}; unroll x2.
    int ht = l >> 4;   // head of dims 2l,2l+1
    float shh = (ht == 0) ? sh.x : (ht == 1) ? sh.y : (ht == 2) ? sh.z : sh.w;
    float seh = (ht == 0) ? se.x : (ht == 1) ? se.y : (ht == 2) ? se.z : se.w;
    float rhinv = 1.f / (shh + 1e-16f);
    float reinv = 1.f / (seh + 1e-16f);
    float2 aE = make_float2(0.f, 0.f), aH = make_float2(0.f, 0.f);
    {
        int e = w;
        for (; e + 2 < deg; e += 4) {
            int j0 = s_src[e], j1 = s_src[e + 2];
            float2 x0 = *(const float2*)&xe[(size_t)j0 * 128 + 2 * l];
            float2 h0 = *(const float2*)&xh[(size_t)j0 * 128 + 2 * l];
            float2 x1 = *(const float2*)&xe[(size_t)j1 * 128 + 2 * l];
            float2 h1 = *(const float2*)&xh[(size_t)j1 * 128 + 2 * l];
            float we0 = s_ae[e * 4 + ht] * reinv;
            float wh0 = s_ah[e * 4 + ht] * rhinv;
            float we1 = s_ae[(e + 2) * 4 + ht] * reinv;
            float wh1 = s_ah[(e + 2) * 4 + ht] * rhinv;
            aE.x += we0 * x0.x + we1 * x1.x;  aE.y += we0 * x0.y + we1 * x1.y;
            aH.x += wh0 * h0.x + wh1 * h1.x;  aH.y += wh0 * h0.y + wh1 * h1.y;
        }
        for (; e < deg; e += 2) {
            int j = s_src[e];
            float2 x0 = *(const float2*)&xe[(size_t)j * 128 + 2 * l];
            float2 h0 = *(const float2*)&xh[(size_t)j * 128 + 2 * l];
            float we0 = s_ae[e * 4 + ht] * reinv;
            float wh0 = s_ah[e * 4 + ht] * rhinv;
            aE.x += we0 * x0.x;  aE.y += we0 * x0.y;
            aH.x += wh0 * h0.x;  aH.y += wh0 * h0.y;
        }
    }
    *(float2*)&s_accE[w][2 * l] = aE;
    *(float2*)&s_accH[w][2 * l] = aH;
    __syncthreads();
    float acc_e = s_accE[0][t] + s_accE[1][t];
    float acc_h = s_accH[0][t] + s_accH[1][t];

    // Phase E: epilogue (per-dim t)
    float e_out = fmaxf(acc_e + b_e[t], 0.f);
    float o_t   = fmaxf(acc_h + b_h[t], 0.f);
    float n2 = bred_sum(o_t * o_t, sred);
    float n_raw = sqrtf(n2), n_c = fmaxf(n_raw, 1e-15f);
    float th = tanhf(n_c);
    float h_out = th / n_c * o_t;
    float nh = th * (n_raw / n_c);
    if (nh > MAXN_BALL) { h_out *= MAXN_BALL / nh; nh = MAXN_BALL; }
    float ne2 = bred_sum(e_out * e_out, sred);
    float nE_raw = sqrtf(ne2), nE_c = fmaxf(nE_raw, 1e-15f);
    float tE = tanhf(nE_c);
    float ye = tE / nE_c * e_out;
    float ny = tE * (nE_raw / nE_c);
    if (ny > MAXN_BALL) { ye *= MAXN_BALL / ny; ny = MAXN_BALL; }
    float xyv = bred_sum(h_out * ye, sred);
    float x2f = nh * nh, y2f = ny * ny;
    float A = 1.f - 2.f * xyv + y2f, B = 1.f - x2f;
    float den = fmaxf(1.f - 2.f * xyv + x2f * y2f, 1e-15f);
    float num2 = fmaxf(A * A * x2f - 2.f * A * B * xyv + B * B * y2f, 0.f);
    float nma = fminf(sqrtf(num2) / den, ART_CLIP);
    float distf = logf((1.f + nma) / (1.f - nma)) * att_hf[0];
    float nyc = fmaxf(ny, 1e-15f);
    float s1 = tanhf(distf * atanh_c(nyc)) / nyc;
    float nxe2 = fabsf(s1) * ny;
    if (nxe2 > MAXN_BALL) { s1 *= MAXN_BALL / nxe2; nxe2 = MAXN_BALL; }
    float xe2v = s1 * ye;
    float xy2 = s1 * xyv;
    float y22 = nxe2 * nxe2;
    float den2 = fmaxf(1.f + 2.f * xy2 + x2f * y22, 1e-15f);
    float hf = ((1.f + 2.f * xy2 + y22) * h_out + (1.f - x2f) * xe2v) / den2;
    float nf2 = bred_sum(hf * hf, sred);
    float nf = sqrtf(nf2);
    if (nf > MAXN_BALL) hf *= MAXN_BALL / nf;
    out[(size_t)i * 128 + t] = hf;
    float nhc = fmaxf(nh, 1e-15f);
    float lh = atanh_c(nhc) / nhc * h_out;
    float diff = lh - e_out;
    float de2 = bred_sum(diff * diff, sred);
    float de = de2 * att_ef[0];
    out[(size_t)N * 128 + (size_t)i * 128 + t] = e_out + de * lh;
}

extern "C" void kernel_launch(void* const* d_in, const int* in_sizes, int n_in,
                              void* d_out, int out_size, void* d_ws, size_t ws_size,
                              hipStream_t stream) {
    const float* x_e      = (const float*)d_in[0];
    const float* x_h      = (const float*)d_in[1];
    const int*   ei       = (const int*)d_in[2];
    const float* W_e      = (const float*)d_in[3];
    const float* b_lin_e  = (const float*)d_in[4];
    const float* att_e    = (const float*)d_in[5];
    const float* b_e      = (const float*)d_in[6];
    const float* W_h      = (const float*)d_in[7];
    const float* b_lin_h  = (const float*)d_in[8];
    const float* att_h    = (const float*)d_in[9];
    const float* b_h      = (const float*)d_in[10];
    const float* att_hf   = (const float*)d_in[11];
    const float* att_ef   = (const float*)d_in[12];

    int N = in_sizes[0] / 128;
    int E = in_sizes[2] / 2;
    int EN = E + N;

    char* ws = (char*)d_ws;
    size_t off = 0;
    auto alloc = [&](size_t bytes) -> void* {
        void* p = ws + off;
        off = (off + bytes + 255) & ~(size_t)255;
        return p;
    };
    float* xe    = (float*)alloc((size_t)N * 128 * 4);
    float* xh    = (float*)alloc((size_t)N * 128 * 4);  // mx then xh (in place)
    float* lam   = (float*)alloc((size_t)N * 4);
    float* ai_g  = (float*)alloc((size_t)N * 4 * 4);
    float* aj_g  = (float*)alloc((size_t)N * 4 * 4);
    float* hi_g  = (float*)alloc((size_t)N * 4 * 4);
    float* hj_g  = (float*)alloc((size_t)N * 4 * 4);
    float* x2h   = (float*)alloc((size_t)N * 4);
    int*   counts= (int*)alloc((size_t)N * 4);
    int*   rowptr= (int*)alloc((size_t)(N + 1) * 4);
    int*   bsums = (int*)alloc(256 * 4);
    int*   srcs  = (int*)alloc((size_t)EN * 4);

    hipMemsetAsync(counts, 0, (size_t)N * 4, stream);

    int gblocks = (N + 31) / 32;
    k_gemm<<<gblocks, 256, 0, stream>>>(x_e, W_e, b_lin_e, xe, N);
    k_gemm<<<gblocks, 256, 0, stream>>>(x_h, W_h, nullptr, xh, N);
    k_node1<<<N, 128, 0, stream>>>(xe, x_h, xh, lam, ai_g, aj_g, hi_g, hj_g, x2h,
                                   att_e, att_h, b_lin_h, N);

    int eblocks = (EN + 255) / 256;
    k_histo<<<eblocks, 256, 0, stream>>>(ei, counts, E, N);
    int nb = (N + 1023) / 1024;
    k_scan_partial<<<nb, 256, 0, stream>>>(counts, bsums, N);
    k_scan_bsums<<<1, 256, 0, stream>>>(bsums, nb, rowptr, N);
    k_scan_final<<<nb, 256, 0, stream>>>(counts, bsums, rowptr, N);
    hipMemsetAsync(counts, 0, (size_t)N * 4, stream);
    k_scatter<<<eblocks, 256, 0, stream>>>(ei, rowptr, counts, srcs, E, N);

    k_node_final<<<N, 128, 0, stream>>>(xh, x2h, lam, xe, hi_g, hj_g, ai_g, aj_g,
                                        rowptr, srcs, b_e, b_h, att_hf, att_ef,
                                        (float*)d_out, N);
}

// Round 3
// 520.135 us; speedup vs baseline: 1.2631x; 1.0459x over previous
//
#include <hip/hip_runtime.h>
#include <math.h>

#define MAXN_BALL (1.0f - 1e-5f)
#define ART_CLIP  (1.0f - 1e-7f)
#define MAXD 128   // max in-degree (incl. self-loop); Poisson(10) => P(>128) ~ 0

__device__ __forceinline__ float atanh_c(float x) {
    x = fminf(x, ART_CLIP);
    return 0.5f * logf((1.0f + x) / (1.0f - x));
}
__device__ __forceinline__ float leaky(float x) { return x > 0.0f ? x : 0.2f * x; }

__device__ __forceinline__ float wred_sum(float v) {
#pragma unroll
    for (int m = 32; m >= 1; m >>= 1) v += __shfl_xor(v, m, 64);
    return v;
}
// block = 128 threads (2 waves)
__device__ __forceinline__ float4 bred_sum4(float4 v, float* s) {
#pragma unroll
    for (int m = 32; m >= 1; m >>= 1) {
        v.x += __shfl_xor(v.x, m, 64); v.y += __shfl_xor(v.y, m, 64);
        v.z += __shfl_xor(v.z, m, 64); v.w += __shfl_xor(v.w, m, 64);
    }
    __syncthreads();
    if ((threadIdx.x & 63) == 0) {
        int w = threadIdx.x >> 6;
        s[w * 4 + 0] = v.x; s[w * 4 + 1] = v.y; s[w * 4 + 2] = v.z; s[w * 4 + 3] = v.w;
    }
    __syncthreads();
    return make_float4(s[0] + s[4], s[1] + s[5], s[2] + s[6], s[3] + s[7]);
}
__device__ __forceinline__ float4 bred_max4(float4 v, float* s) {
#pragma unroll
    for (int m = 32; m >= 1; m >>= 1) {
        v.x = fmaxf(v.x, __shfl_xor(v.x, m, 64)); v.y = fmaxf(v.y, __shfl_xor(v.y, m, 64));
        v.z = fmaxf(v.z, __shfl_xor(v.z, m, 64)); v.w = fmaxf(v.w, __shfl_xor(v.w, m, 64));
    }
    __syncthreads();
    if ((threadIdx.x & 63) == 0) {
        int w = threadIdx.x >> 6;
        s[w * 4 + 0] = v.x; s[w * 4 + 1] = v.y; s[w * 4 + 2] = v.z; s[w * 4 + 3] = v.w;
    }
    __syncthreads();
    return make_float4(fmaxf(s[0], s[4]), fmaxf(s[1], s[5]), fmaxf(s[2], s[6]), fmaxf(s[3], s[7]));
}

// ---------------- GEMM: Y[r][o] = sum_k X[r][k]*W[o][k] (+ bias[o]) ----------------
__global__ __launch_bounds__(256) void k_gemm(const float* __restrict__ X,
                                              const float* __restrict__ W,
                                              const float* __restrict__ bias,
                                              float* __restrict__ Y, int N) {
    __shared__ float xs[32][128];
    __shared__ float wT[64][132];   // [k][o], padded stride 132
    int t = threadIdx.x;
    int r0 = blockIdx.x * 32;
    for (int idx = t; idx < 32 * 128; idx += 256) {
        int r = idx >> 7, k = idx & 127;
        int gr = r0 + r;
        xs[r][k] = (gr < N) ? X[(size_t)gr * 128 + k] : 0.0f;
    }
    int rg = t >> 5;    // rows rg*4..rg*4+3
    int cg = t & 31;    // cols cg*4..cg*4+3
    float acc[4][4] = {};
    for (int kk = 0; kk < 128; kk += 64) {
        __syncthreads();
        for (int idx = t; idx < 128 * 64; idx += 256) {
            int o = idx >> 6;
            int k = idx & 63;
            wT[k][o] = W[(size_t)o * 128 + kk + k];
        }
        __syncthreads();
#pragma unroll
        for (int k4 = 0; k4 < 64; k4 += 4) {
            float4 xr0 = *(const float4*)&xs[rg * 4 + 0][kk + k4];
            float4 xr1 = *(const float4*)&xs[rg * 4 + 1][kk + k4];
            float4 xr2 = *(const float4*)&xs[rg * 4 + 2][kk + k4];
            float4 xr3 = *(const float4*)&xs[rg * 4 + 3][kk + k4];
            float4 w0 = *(const float4*)&wT[k4 + 0][cg * 4];
            float4 w1 = *(const float4*)&wT[k4 + 1][cg * 4];
            float4 w2 = *(const float4*)&wT[k4 + 2][cg * 4];
            float4 w3 = *(const float4*)&wT[k4 + 3][cg * 4];
#define GEMM_J(j, xr)                                                     \
            acc[j][0] += xr.x * w0.x + xr.y * w1.x + xr.z * w2.x + xr.w * w3.x; \
            acc[j][1] += xr.x * w0.y + xr.y * w1.y + xr.z * w2.y + xr.w * w3.y; \
            acc[j][2] += xr.x * w0.z + xr.y * w1.z + xr.z * w2.z + xr.w * w3.z; \
            acc[j][3] += xr.x * w0.w + xr.y * w1.w + xr.z * w2.w + xr.w * w3.w;
            GEMM_J(0, xr0) GEMM_J(1, xr1) GEMM_J(2, xr2) GEMM_J(3, xr3)
#undef GEMM_J
        }
    }
    float4 b4 = make_float4(0.f, 0.f, 0.f, 0.f);
    if (bias) b4 = *(const float4*)&bias[cg * 4];
#pragma unroll
    for (int j = 0; j < 4; ++j) {
        int gr = r0 + rg * 4 + j;
        if (gr < N) {
            float4 o4 = make_float4(acc[j][0] + b4.x, acc[j][1] + b4.y,
                                    acc[j][2] + b4.z, acc[j][3] + b4.w);
            *(float4*)&Y[(size_t)gr * 128 + cg * 4] = o4;
        }
    }
}

// ---------------- Per-node stage (one 4-wide reduction, analytic norms) ----------------
__global__ __launch_bounds__(128) void k_node1(const float* __restrict__ xe,
                                               const float* __restrict__ x_h,
                                               float* __restrict__ xh,
                                               float* __restrict__ lam_g,
                                               float* __restrict__ ai_g, float* __restrict__ aj_g,
                                               float* __restrict__ hi_g, float* __restrict__ hj_g,
                                               float* __restrict__ x2h,
                                               const float* __restrict__ att_e,
                                               const float* __restrict__ att_h,
                                               const float* __restrict__ b_lin_h, int N) {
    __shared__ float sred[8];
    int i = blockIdx.x, t = threadIdx.x;
    size_t base = (size_t)i * 128 + t;
    int hh = t >> 5, dd = t & 31;

    // Euclidean attention scalars
    float xev = xe[base];
    float pi = xev * att_e[hh * 64 + dd];
    float pj = xev * att_e[hh * 64 + 32 + dd];
#pragma unroll
    for (int m = 1; m <= 16; m <<= 1) { pi += __shfl_xor(pi, m, 64); pj += __shfl_xor(pj, m, 64); }
    if (dd == 0) { ai_g[i * 4 + hh] = pi; aj_g[i * 4 + hh] = pj; }

    float xv  = x_h[base];
    float mxv = xh[base];     // mx
    float bv  = b_lin_h[t];
    // one batched reduction: |x|^2, |mx|^2, |b|^2, <mx,b>
    float4 R = bred_sum4(make_float4(xv * xv, mxv * mxv, bv * bv, mxv * bv), sred);
    float nx2 = R.x, nmx2 = R.y, nb2 = R.z, dmb = R.w;

    float nxr = sqrtf(nx2),  nxc = fmaxf(nxr, 1e-15f);
    float nmxr = sqrtf(nmx2), nmxc = fmaxf(nmxr, 1e-15f);
    float tt = tanhf(nmxc / nxc * atanh_c(nxc));
    float c_m = tt / nmxc;                    // mv = c_m * mx
    float nmv = tt * (nmxr / nmxc);
    if (nmv > MAXN_BALL) { c_m *= MAXN_BALL / nmv; nmv = MAXN_BALL; }

    float nbr = sqrtf(nb2), nbc = fmaxf(nbr, 1e-15f);
    float tb = tanhf(nbc);
    float c_b = tb / nbc;                     // hb = c_b * b
    float nhb = tb * (nbr / nbc);
    if (nhb > MAXN_BALL) { c_b *= MAXN_BALL / nhb; nhb = MAXN_BALL; }

    float xy = c_m * c_b * dmb;
    float x2 = nmv * nmv, y2 = nhb * nhb;
    float den = fmaxf(1.f + 2.f * xy + x2 * y2, 1e-15f);
    float al = (1.f + 2.f * xy + y2) * c_m / den;  // xh = al*mx + be*b
    float be = (1.f - x2) * c_b / den;
    float nr2 = al * al * nmx2 + 2.f * al * be * dmb + be * be * nb2;
    float nrr = sqrtf(nr2);
    if (nrr > MAXN_BALL) { float sc = MAXN_BALL / nrr; al *= sc; be *= sc; nrr = MAXN_BALL; }
    float resv = al * mxv + be * bv;
    xh[base] = resv;

    float nnc = fmaxf(nrr, 1e-15f);
    float lam = atanh_c(nnc) / nnc;
    if (t == 0) { x2h[i] = nrr * nrr; lam_g[i] = lam; }
    float lxv = lam * resv;

    float qi = lxv * att_h[hh * 64 + dd];
    float qj = lxv * att_h[hh * 64 + 32 + dd];
#pragma unroll
    for (int m = 1; m <= 16; m <<= 1) { qi += __shfl_xor(qi, m, 64); qj += __shfl_xor(qj, m, 64); }
    if (dd == 0) { hi_g[i * 4 + hh] = qi; hj_g[i * 4 + hh] = qj; }
}

// ---------------- CSR build ----------------
__global__ void k_histo(const int* __restrict__ ei, int* __restrict__ counts, int E, int N) {
    int idx = blockIdx.x * blockDim.x + threadIdx.x;
    if (idx >= E + N) return;
    int d = (idx < E) ? ei[E + idx] : (idx - E);
    atomicAdd(&counts[d], 1);
}
__global__ __launch_bounds__(256) void k_scan_partial(const int* __restrict__ counts,
                                                      int* __restrict__ bsums, int N) {
    __shared__ int sw[4];
    int s = 0;
    int base = blockIdx.x * 1024;
    for (int j = threadIdx.x; j < 1024; j += 256) {
        int idx = base + j;
        if (idx < N) s += counts[idx];
    }
#pragma unroll
    for (int m = 32; m >= 1; m >>= 1) s += __shfl_xor(s, m, 64);
    if ((threadIdx.x & 63) == 0) sw[threadIdx.x >> 6] = s;
    __syncthreads();
    if (threadIdx.x == 0) bsums[blockIdx.x] = sw[0] + sw[1] + sw[2] + sw[3];
}
__global__ __launch_bounds__(256) void k_scan_bsums(int* __restrict__ bsums, int nb,
                                                    int* __restrict__ rowptr, int N) {
    __shared__ int ss[256];
    int t = threadIdx.x;
    int v = (t < nb) ? bsums[t] : 0;
    ss[t] = v; __syncthreads();
    for (int off = 1; off < 256; off <<= 1) {
        int u = (t >= off) ? ss[t - off] : 0;
        __syncthreads();
        ss[t] += u;
        __syncthreads();
    }
    if (t < nb) bsums[t] = ss[t] - v;
    if (t == 255) rowptr[N] = ss[255];
}
__global__ __launch_bounds__(256) void k_scan_final(const int* __restrict__ counts,
                                                    const int* __restrict__ bsums,
                                                    int* __restrict__ rowptr, int N) {
    __shared__ int ss[256];
    int t = threadIdx.x;
    int base = blockIdx.x * 1024 + t * 4;
    int v0 = (base + 0 < N) ? counts[base + 0] : 0;
    int v1 = (base + 1 < N) ? counts[base + 1] : 0;
    int v2 = (base + 2 < N) ? counts[base + 2] : 0;
    int v3 = (base + 3 < N) ? counts[base + 3] : 0;
    int tot = v0 + v1 + v2 + v3;
    ss[t] = tot; __syncthreads();
    for (int off = 1; off < 256; off <<= 1) {
        int u = (t >= off) ? ss[t - off] : 0;
        __syncthreads();
        ss[t] += u;
        __syncthreads();
    }
    int excl = ss[t] - tot + bsums[blockIdx.x];
    if (base + 0 < N) rowptr[base + 0] = excl;
    if (base + 1 < N) rowptr[base + 1] = excl + v0;
    if (base + 2 < N) rowptr[base + 2] = excl + v0 + v1;
    if (base + 3 < N) rowptr[base + 3] = excl + v0 + v1 + v2;
}
__global__ void k_scatter(const int* __restrict__ ei, const int* __restrict__ rowptr,
                          int* __restrict__ cursor, int* __restrict__ srcs, int E, int N) {
    int idx = blockIdx.x * blockDim.x + threadIdx.x;
    if (idx >= E + N) return;
    int s, d;
    if (idx < E) { s = ei[idx]; d = ei[E + idx]; } else { s = d = idx - E; }
    int p = rowptr[d] + atomicAdd(&cursor[d], 1);
    srcs[p] = s;
}

// ---------------- Final per-node kernel ----------------
__global__ __launch_bounds__(128) void k_node_final(
    const float* __restrict__ xh, const float* __restrict__ x2h,
    const float* __restrict__ lam_g, const float* __restrict__ xe,
    const float* __restrict__ hi_g, const float* __restrict__ hj_g,
    const float* __restrict__ ai_g, const float* __restrict__ aj_g,
    const int* __restrict__ rowptr, const int* __restrict__ srcs,
    const float* __restrict__ b_e, const float* __restrict__ b_h,
    const float* __restrict__ att_hf, const float* __restrict__ att_ef,
    float* __restrict__ out, int N) {
    __shared__ float sxh[128];
    __shared__ int   s_src[MAXD];
    __shared__ float s_d[MAXD];
    __shared__ float s_ah[MAXD * 4];
    __shared__ float s_ae[MAXD * 4];
    __shared__ float s_accE[2][128];
    __shared__ float s_accH[2][128];
    __shared__ float sred[8];

    int i = blockIdx.x;
    int t = threadIdx.x;
    int w = t >> 6, l = t & 63;
    int rs = rowptr[i];
    int deg = rowptr[i + 1] - rs;
    if (deg > MAXD) deg = MAXD;

    sxh[t] = xh[(size_t)i * 128 + t];
    for (int e = t; e < deg; e += 128) s_src[e] = srcs[rs + e];
    __syncthreads();

    float x2i = x2h[i];

    // Phase A: distances. 8 lanes/edge, 16 dims/lane (4x float4), 16 edges per block pass.
    {
        int g = l & 7;            // dim-segment within edge group
        int sub = l >> 3;         // edge-within-wave 0..7
        float4 sx0 = *(const float4*)&sxh[g * 16 + 0];
        float4 sx1 = *(const float4*)&sxh[g * 16 + 4];
        float4 sx2 = *(const float4*)&sxh[g * 16 + 8];
        float4 sx3 = *(const float4*)&sxh[g * 16 + 12];
        for (int p = 0; p * 16 < deg; ++p) {
            int e = p * 16 + w * 8 + sub;
            bool act = e < deg;
            float dot = 0.f;
            float y2 = 0.f;
            int j = 0;
            if (act) {
                j = s_src[e];
                const float4* rp = (const float4*)&xh[(size_t)j * 128 + g * 16];
                float4 a0 = rp[0], a1 = rp[1], a2 = rp[2], a3 = rp[3];
                y2 = x2h[j];
                dot = a0.x * sx0.x + a0.y * sx0.y + a0.z * sx0.z + a0.w * sx0.w
                    + a1.x * sx1.x + a1.y * sx1.y + a1.z * sx1.z + a1.w * sx1.w
                    + a2.x * sx2.x + a2.y * sx2.y + a2.z * sx2.z + a2.w * sx2.w
                    + a3.x * sx3.x + a3.y * sx3.y + a3.z * sx3.z + a3.w * sx3.w;
            }
            dot += __shfl_xor(dot, 1, 64);
            dot += __shfl_xor(dot, 2, 64);
            dot += __shfl_xor(dot, 4, 64);
            if (act) {
                float xy = dot;
                float A = 1.f - 2.f * xy + y2;
                float B = 1.f - x2i;
                float den = fmaxf(1.f - 2.f * xy + x2i * y2, 1e-15f);
                float num2 = fmaxf(A * A * x2i - 2.f * A * B * xy + B * B * y2, 0.f);
                float nma = fminf(sqrtf(num2) / den, ART_CLIP);
                if (g == 0) s_d[e] = logf((1.f + nma) / (1.f - nma));  // 2*artanh
            }
        }
    }
    __syncthreads();

    // Phase B: softmax over distances
    float lm = -INFINITY;
    for (int e = t; e < deg; e += 128) lm = fmaxf(lm, s_d[e]);
    float4 mdv = bred_max4(make_float4(lm, -INFINITY, -INFINITY, -INFINITY), sred);
    float md = mdv.x;
    float lsum = 0.f;
    for (int e = t; e < deg; e += 128) { float ex = expf(s_d[e] - md); s_d[e] = ex; lsum += ex; }
    float4 sdv = bred_sum4(make_float4(lsum, 0.f, 0.f, 0.f), sred);
    float dinv = 1.f / (sdv.x + 1e-16f);

    // Phase C: per-edge per-head logits + softmaxes
    float4 hi4 = *(const float4*)&hi_g[i * 4];
    float4 ai4 = *(const float4*)&ai_g[i * 4];
    float4 mh = make_float4(-INFINITY, -INFINITY, -INFINITY, -INFINITY);
    float4 me = mh;
    for (int e = t; e < deg; e += 128) {
        int j = s_src[e];
        float ds = s_d[e] * dinv;
        float4 hj4 = *(const float4*)&hj_g[j * 4];
        float4 aj4 = *(const float4*)&aj_g[j * 4];
        float4 vh, ve;
        vh.x = leaky((hi4.x + hj4.x) * ds); vh.y = leaky((hi4.y + hj4.y) * ds);
        vh.z = leaky((hi4.z + hj4.z) * ds); vh.w = leaky((hi4.w + hj4.w) * ds);
        ve.x = leaky(ai4.x + aj4.x); ve.y = leaky(ai4.y + aj4.y);
        ve.z = leaky(ai4.z + aj4.z); ve.w = leaky(ai4.w + aj4.w);
        *(float4*)&s_ah[e * 4] = vh;
        *(float4*)&s_ae[e * 4] = ve;
        mh.x = fmaxf(mh.x, vh.x); mh.y = fmaxf(mh.y, vh.y); mh.z = fmaxf(mh.z, vh.z); mh.w = fmaxf(mh.w, vh.w);
        me.x = fmaxf(me.x, ve.x); me.y = fmaxf(me.y, ve.y); me.z = fmaxf(me.z, ve.z); me.w = fmaxf(me.w, ve.w);
    }
    mh = bred_max4(mh, sred);
    me = bred_max4(me, sred);
    float4 sh = make_float4(0.f, 0.f, 0.f, 0.f), se = sh;
    for (int e = t; e < deg; e += 128) {
        float4 vh = *(float4*)&s_ah[e * 4];
        float4 ve = *(float4*)&s_ae[e * 4];
        vh.x = expf(vh.x - mh.x); vh.y = expf(vh.y - mh.y); vh.z = expf(vh.z - mh.z); vh.w = expf(vh.w - mh.w);
        ve.x = expf(ve.x - me.x); ve.y = expf(ve.y - me.y); ve.z = expf(ve.z - me.z); ve.w = expf(ve.w - me.w);
        *(float4*)&s_ah[e * 4] = vh;
        *(float4*)&s_ae[e * 4] = ve;
        sh.x += vh.x; sh.y += vh.y; sh.z += vh.z; sh.w += vh.w;
        se.x += ve.x; se.y += ve.y; se.z += ve.z; se.w += ve.w;
    }
    sh = bred_sum4(sh, sred);
    se = bred_sum4(se, sred);
    // Normalize weights in place; fold lam_j into hyperbolic weights.
    float4 rh = make_float4(1.f / (sh.x + 1e-16f), 1.f / (sh.y + 1e-16f),
                            1.f / (sh.z + 1e-16f), 1.f / (sh.w + 1e-16f));
    float4 re = make_float4(1.f / (se.x + 1e-16f), 1.f / (se.y + 1e-16f),
                            1.f / (se.z + 1e-16f), 1.f / (se.w + 1e-16f));
    for (int e = t; e < deg; e += 128) {
        int j = s_src[e];
        float lamj = lam_g[j];
        float4 vh = *(float4*)&s_ah[e * 4];
        float4 ve = *(float4*)&s_ae[e * 4];
        vh.x *= rh.x * lamj; vh.y *= rh.y * lamj; vh.z *= rh.z * lamj; vh.w *= rh.w * lamj;
        ve.x *= re.x; ve.y *= re.y; ve.z *= re.z; ve.w *= re.w;
        *(float4*)&s_ah[e * 4] = vh;
        *(float4*)&s_ae[e * 4] = ve;
    }
    __syncthreads();

    // Phase D: aggregation. Half-wave per edge, lane covers 4 dims (float4).
    int lh = l >> 5, q = l & 31;          // dims 4q..4q+3, head = q>>3
    float4 aE = make_float4(0.f, 0.f, 0.f, 0.f), aH = aE;
    for (int e = 2 * w + lh; e < deg; e += 4) {
        int j = s_src[e];
        float4 xv = *(const float4*)&xe[(size_t)j * 128 + 4 * q];
        float4 hv = *(const float4*)&xh[(size_t)j * 128 + 4 * q];
        float we = s_ae[e * 4 + (q >> 3)];
        float wh = s_ah[e * 4 + (q >> 3)];
        aE.x += we * xv.x; aE.y += we * xv.y; aE.z += we * xv.z; aE.w += we * xv.w;
        aH.x += wh * hv.x; aH.y += wh * hv.y; aH.z += wh * hv.z; aH.w += wh * hv.w;
    }
    aE.x += __shfl_xor(aE.x, 32, 64); aE.y += __shfl_xor(aE.y, 32, 64);
    aE.z += __shfl_xor(aE.z, 32, 64); aE.w += __shfl_xor(aE.w, 32, 64);
    aH.x += __shfl_xor(aH.x, 32, 64); aH.y += __shfl_xor(aH.y, 32, 64);
    aH.z += __shfl_xor(aH.z, 32, 64); aH.w += __shfl_xor(aH.w, 32, 64);
    if (lh == 0) {
        *(float4*)&s_accE[w][4 * q] = aE;
        *(float4*)&s_accH[w][4 * q] = aH;
    }
    __syncthreads();
    float acc_e = s_accE[0][t] + s_accE[1][t];
    float acc_h = s_accH[0][t] + s_accH[1][t];

    // Phase E: epilogue — ONE batched reduction, everything else analytic.
    float e_out = fmaxf(acc_e + b_e[t], 0.f);
    float o_t   = fmaxf(acc_h + b_h[t], 0.f);
    float4 R = bred_sum4(make_float4(o_t * o_t, e_out * e_out, o_t * e_out, 0.f), sred);
    float n2 = R.x, ne2 = R.y, dot3 = R.z;

    float n_raw = sqrtf(n2), n_c = fmaxf(n_raw, 1e-15f);
    float th = tanhf(n_c);
    float c_h = th / n_c;                    // h_out = c_h * o_t
    float nh = th * (n_raw / n_c);
    if (nh > MAXN_BALL) { c_h *= MAXN_BALL / nh; nh = MAXN_BALL; }

    float nE_raw = sqrtf(ne2), nE_c = fmaxf(nE_raw, 1e-15f);
    float tE = tanhf(nE_c);
    float c_e = tE / nE_c;                   // ye = c_e * e_out
    float ny = tE * (nE_raw / nE_c);
    if (ny > MAXN_BALL) { c_e *= MAXN_BALL / ny; ny = MAXN_BALL; }

    float xyv = c_h * c_e * dot3;
    float x2f = nh * nh, y2f = ny * ny;
    float A = 1.f - 2.f * xyv + y2f, B = 1.f - x2f;
    float den = fmaxf(1.f - 2.f * xyv + x2f * y2f, 1e-15f);
    float num2 = fmaxf(A * A * x2f - 2.f * A * B * xyv + B * B * y2f, 0.f);
    float nma = fminf(sqrtf(num2) / den, ART_CLIP);
    float distf = logf((1.f + nma) / (1.f - nma)) * att_hf[0];
    float nyc = fmaxf(ny, 1e-15f);
    float s1 = tanhf(distf * atanh_c(nyc)) / nyc;     // xe2 = s1 * ye
    float nxe2 = fabsf(s1) * ny;
    if (nxe2 > MAXN_BALL) { s1 *= MAXN_BALL / nxe2; nxe2 = MAXN_BALL; }
    float xy2 = s1 * xyv;
    float y22 = nxe2 * nxe2;
    float den2 = fmaxf(1.f + 2.f * xy2 + x2f * y22, 1e-15f);
    float alpha = (1.f + 2.f * xy2 + y22) / den2 * c_h;        // hf = alpha*o_t + beta*e_out
    float beta  = (1.f - x2f) * s1 / den2 * c_e;
    float nf2 = alpha * alpha * n2 + 2.f * alpha * beta * dot3 + beta * beta * ne2;
    float nf = sqrtf(nf2);
    if (nf > MAXN_BALL) { float sc = MAXN_BALL / nf; alpha *= sc; beta *= sc; }
    out[(size_t)i * 128 + t] = alpha * o_t + beta * e_out;

    float nhc = fmaxf(nh, 1e-15f);
    float gam = atanh_c(nhc) / nhc * c_h;            // lh = gam * o_t
    float de2 = gam * gam * n2 - 2.f * gam * dot3 + ne2;
    float de = de2 * att_ef[0];
    out[(size_t)N * 128 + (size_t)i * 128 + t] = e_out + de * gam * o_t;
}

extern "C" void kernel_launch(void* const* d_in, const int* in_sizes, int n_in,
                              void* d_out, int out_size, void* d_ws, size_t ws_size,
                              hipStream_t stream) {
    const float* x_e      = (const float*)d_in[0];
    const float* x_h      = (const float*)d_in[1];
    const int*   ei       = (const int*)d_in[2];
    const float* W_e      = (const float*)d_in[3];
    const float* b_lin_e  = (const float*)d_in[4];
    const float* att_e    = (const float*)d_in[5];
    const float* b_e      = (const float*)d_in[6];
    const float* W_h      = (const float*)d_in[7];
    const float* b_lin_h  = (const float*)d_in[8];
    const float* att_h    = (const float*)d_in[9];
    const float* b_h      = (const float*)d_in[10];
    const float* att_hf   = (const float*)d_in[11];
    const float* att_ef   = (const float*)d_in[12];

    int N = in_sizes[0] / 128;
    int E = in_sizes[2] / 2;
    int EN = E + N;

    char* ws = (char*)d_ws;
    size_t off = 0;
    auto alloc = [&](size_t bytes) -> void* {
        void* p = ws + off;
        off = (off + bytes + 255) & ~(size_t)255;
        return p;
    };
    float* xe    = (float*)alloc((size_t)N * 128 * 4);
    float* xh    = (float*)alloc((size_t)N * 128 * 4);  // mx then xh (in place)
    float* lam   = (float*)alloc((size_t)N * 4);
    float* ai_g  = (float*)alloc((size_t)N * 4 * 4);
    float* aj_g  = (float*)alloc((size_t)N * 4 * 4);
    float* hi_g  = (float*)alloc((size_t)N * 4 * 4);
    float* hj_g  = (float*)alloc((size_t)N * 4 * 4);
    float* x2h   = (float*)alloc((size_t)N * 4);
    int*   counts= (int*)alloc((size_t)N * 4);
    int*   rowptr= (int*)alloc((size_t)(N + 1) * 4);
    int*   bsums = (int*)alloc(256 * 4);
    int*   srcs  = (int*)alloc((size_t)EN * 4);

    hipMemsetAsync(counts, 0, (size_t)N * 4, stream);

    int gblocks = (N + 31) / 32;
    k_gemm<<<gblocks, 256, 0, stream>>>(x_e, W_e, b_lin_e, xe, N);
    k_gemm<<<gblocks, 256, 0, stream>>>(x_h, W_h, nullptr, xh, N);
    k_node1<<<N, 128, 0, stream>>>(xe, x_h, xh, lam, ai_g, aj_g, hi_g, hj_g, x2h,
                                   att_e, att_h, b_lin_h, N);

    int eblocks = (EN + 255) / 256;
    k_histo<<<eblocks, 256, 0, stream>>>(ei, counts, E, N);
    int nb = (N + 1023) / 1024;
    k_scan_partial<<<nb, 256, 0, stream>>>(counts, bsums, N);
    k_scan_bsums<<<1, 256, 0, stream>>>(bsums, nb, rowptr, N);
    k_scan_final<<<nb, 256, 0, stream>>>(counts, bsums, rowptr, N);
    hipMemsetAsync(counts, 0, (size_t)N * 4, stream);
    k_scatter<<<eblocks, 256, 0, stream>>>(ei, rowptr, counts, srcs, E, N);

    k_node_final<<<N, 128, 0, stream>>>(xh, x2h, lam, xe, hi_g, hj_g, ai_g, aj_g,
                                        rowptr, srcs, b_e, b_h, att_hf, att_ef,
                                        (float*)d_out, N);
}

// Round 4
// 425.737 us; speedup vs baseline: 1.5432x; 1.2217x over previous
//
#include <hip/hip_runtime.h>
#include <math.h>

#define MAXN_BALL (1.0f - 1e-5f)
#define ART_CLIP  (1.0f - 1e-7f)
#define MAXD 128   // max in-degree (incl. self-loop); Poisson(10) => P(>128) ~ 0

// ---- fast scalar math: single-instruction hardware ops (v_exp/v_log/v_rcp) ----
__device__ __forceinline__ float f_rcp(float x)  { return __builtin_amdgcn_rcpf(x); }
__device__ __forceinline__ float f_exp(float x)  { return __expf(x); }
__device__ __forceinline__ float f_log(float x)  { return __logf(x); }
__device__ __forceinline__ float f_tanh(float x) {
    float ax = fabsf(x);
    float e = __expf(2.f * ax);
    float t = 1.f - 2.f * f_rcp(e + 1.f);
    return copysignf(t, x);
}
__device__ __forceinline__ float f_atanh(float x) {   // x >= 0
    x = fminf(x, ART_CLIP);
    return 0.5f * f_log((1.f + x) * f_rcp(1.f - x));
}
__device__ __forceinline__ float leaky(float x) { return x > 0.0f ? x : 0.2f * x; }

__device__ __forceinline__ float wred_sum(float v) {
#pragma unroll
    for (int m = 32; m >= 1; m >>= 1) v += __shfl_xor(v, m, 64);
    return v;
}
__device__ __forceinline__ float wred_max(float v) {
#pragma unroll
    for (int m = 32; m >= 1; m >>= 1) v = fmaxf(v, __shfl_xor(v, m, 64));
    return v;
}

// ---------------- Fused GEMM: Y[r][o] = sum_k X[r][k]*W[o][k] (+ bias[o]) ----------------
// blockIdx.y selects problem (0: x_e/W_e/b_lin_e -> xe, 1: x_h/W_h -> mx)
__global__ __launch_bounds__(256) void k_gemm2(const float* __restrict__ X0,
                                               const float* __restrict__ X1,
                                               const float* __restrict__ W0,
                                               const float* __restrict__ W1,
                                               const float* __restrict__ bias0,
                                               float* __restrict__ Y0,
                                               float* __restrict__ Y1, int N) {
    const float* X = blockIdx.y ? X1 : X0;
    const float* W = blockIdx.y ? W1 : W0;
    const float* bias = blockIdx.y ? nullptr : bias0;
    float* Y = blockIdx.y ? Y1 : Y0;
    __shared__ float xs[32][128];
    __shared__ float wT[64][132];
    int t = threadIdx.x;
    int r0 = blockIdx.x * 32;
    for (int idx = t; idx < 32 * 128; idx += 256) {
        int r = idx >> 7, k = idx & 127;
        int gr = r0 + r;
        xs[r][k] = (gr < N) ? X[(size_t)gr * 128 + k] : 0.0f;
    }
    int rg = t >> 5;
    int cg = t & 31;
    float acc[4][4] = {};
    for (int kk = 0; kk < 128; kk += 64) {
        __syncthreads();
        for (int idx = t; idx < 128 * 64; idx += 256) {
            int o = idx >> 6;
            int k = idx & 63;
            wT[k][o] = W[(size_t)o * 128 + kk + k];
        }
        __syncthreads();
#pragma unroll
        for (int k4 = 0; k4 < 64; k4 += 4) {
            float4 xr0 = *(const float4*)&xs[rg * 4 + 0][kk + k4];
            float4 xr1 = *(const float4*)&xs[rg * 4 + 1][kk + k4];
            float4 xr2 = *(const float4*)&xs[rg * 4 + 2][kk + k4];
            float4 xr3 = *(const float4*)&xs[rg * 4 + 3][kk + k4];
            float4 w0 = *(const float4*)&wT[k4 + 0][cg * 4];
            float4 w1 = *(const float4*)&wT[k4 + 1][cg * 4];
            float4 w2 = *(const float4*)&wT[k4 + 2][cg * 4];
            float4 w3 = *(const float4*)&wT[k4 + 3][cg * 4];
#define GEMM_J(j, xr)                                                     \
            acc[j][0] += xr.x * w0.x + xr.y * w1.x + xr.z * w2.x + xr.w * w3.x; \
            acc[j][1] += xr.x * w0.y + xr.y * w1.y + xr.z * w2.y + xr.w * w3.y; \
            acc[j][2] += xr.x * w0.z + xr.y * w1.z + xr.z * w2.z + xr.w * w3.z; \
            acc[j][3] += xr.x * w0.w + xr.y * w1.w + xr.z * w2.w + xr.w * w3.w;
            GEMM_J(0, xr0) GEMM_J(1, xr1) GEMM_J(2, xr2) GEMM_J(3, xr3)
#undef GEMM_J
        }
    }
    float4 b4 = make_float4(0.f, 0.f, 0.f, 0.f);
    if (bias) b4 = *(const float4*)&bias[cg * 4];
#pragma unroll
    for (int j = 0; j < 4; ++j) {
        int gr = r0 + rg * 4 + j;
        if (gr < N) {
            float4 o4 = make_float4(acc[j][0] + b4.x, acc[j][1] + b4.y,
                                    acc[j][2] + b4.z, acc[j][3] + b4.w);
            *(float4*)&Y[(size_t)gr * 128 + cg * 4] = o4;
        }
    }
}

// ---------------- Per-node stage: wave-per-node, shuffle-only reductions ----------------
__global__ __launch_bounds__(256) void k_node1(const float* __restrict__ xe,
                                               const float* __restrict__ x_h,
                                               float* __restrict__ xh,
                                               float* __restrict__ lam_g,
                                               float* __restrict__ ai_g, float* __restrict__ aj_g,
                                               float* __restrict__ hi_g, float* __restrict__ hj_g,
                                               float* __restrict__ x2h,
                                               const float* __restrict__ att_e,
                                               const float* __restrict__ att_h,
                                               const float* __restrict__ b_lin_h, int N) {
    int wv = threadIdx.x >> 6, l = threadIdx.x & 63;
    int i = blockIdx.x * 4 + wv;
    if (i >= N) return;
    size_t base = (size_t)i * 128 + 2 * l;
    int ht = l >> 4;             // head of dims 2l,2l+1
    int d0 = (l & 15) * 2;       // position within head

    // Euclidean attention scalars (per-head 16-lane reductions)
    float2 xe2 = *(const float2*)&xe[base];
    float2 aeT = *(const float2*)&att_e[ht * 64 + d0];
    float2 aeS = *(const float2*)&att_e[ht * 64 + 32 + d0];
    float pi = xe2.x * aeT.x + xe2.y * aeT.y;
    float pj = xe2.x * aeS.x + xe2.y * aeS.y;
#pragma unroll
    for (int m = 1; m <= 8; m <<= 1) { pi += __shfl_xor(pi, m, 64); pj += __shfl_xor(pj, m, 64); }
    if ((l & 15) == 0) { ai_g[i * 4 + ht] = pi; aj_g[i * 4 + ht] = pj; }

    float2 xv  = *(const float2*)&x_h[base];
    float2 mxv = *(const float2*)&xh[base];       // mx
    float2 bv  = *(const float2*)&b_lin_h[2 * l];
    float nx2  = xv.x * xv.x + xv.y * xv.y;
    float nmx2 = mxv.x * mxv.x + mxv.y * mxv.y;
    float nb2  = bv.x * bv.x + bv.y * bv.y;
    float dmb  = mxv.x * bv.x + mxv.y * bv.y;
#pragma unroll
    for (int m = 32; m >= 1; m >>= 1) {
        nx2 += __shfl_xor(nx2, m, 64); nmx2 += __shfl_xor(nmx2, m, 64);
        nb2 += __shfl_xor(nb2, m, 64); dmb  += __shfl_xor(dmb, m, 64);
    }

    float nxr = sqrtf(nx2),  nxc = fmaxf(nxr, 1e-15f);
    float nmxr = sqrtf(nmx2), nmxc = fmaxf(nmxr, 1e-15f);
    float tt = f_tanh(nmxc * f_rcp(nxc) * f_atanh(nxc));
    float c_m = tt * f_rcp(nmxc);                 // mv = c_m * mx
    float nmv = tt * (nmxr * f_rcp(nmxc));
    if (nmv > MAXN_BALL) { c_m *= MAXN_BALL / nmv; nmv = MAXN_BALL; }

    float nbr = sqrtf(nb2), nbc = fmaxf(nbr, 1e-15f);
    float tb = f_tanh(nbc);
    float c_b = tb * f_rcp(nbc);                  // hb = c_b * b
    float nhb = tb * (nbr * f_rcp(nbc));
    if (nhb > MAXN_BALL) { c_b *= MAXN_BALL / nhb; nhb = MAXN_BALL; }

    float xy = c_m * c_b * dmb;
    float x2 = nmv * nmv, y2 = nhb * nhb;
    float den = fmaxf(1.f + 2.f * xy + x2 * y2, 1e-15f);
    float rden = f_rcp(den);
    float al = (1.f + 2.f * xy + y2) * c_m * rden;   // xh = al*mx + be*b
    float be = (1.f - x2) * c_b * rden;
    float nr2 = al * al * nmx2 + 2.f * al * be * dmb + be * be * nb2;
    float nrr = sqrtf(nr2);
    if (nrr > MAXN_BALL) { float sc = MAXN_BALL / nrr; al *= sc; be *= sc; nrr = MAXN_BALL; }
    float2 resv = make_float2(al * mxv.x + be * bv.x, al * mxv.y + be * bv.y);
    *(float2*)&xh[base] = resv;

    float nnc = fmaxf(nrr, 1e-15f);
    float lam = f_atanh(nnc) * f_rcp(nnc);
    if (l == 0) { x2h[i] = nrr * nrr; lam_g[i] = lam; }

    float2 lxv = make_float2(lam * resv.x, lam * resv.y);
    float2 ahT = *(const float2*)&att_h[ht * 64 + d0];
    float2 ahS = *(const float2*)&att_h[ht * 64 + 32 + d0];
    float qi = lxv.x * ahT.x + lxv.y * ahT.y;
    float qj = lxv.x * ahS.x + lxv.y * ahS.y;
#pragma unroll
    for (int m = 1; m <= 8; m <<= 1) { qi += __shfl_xor(qi, m, 64); qj += __shfl_xor(qj, m, 64); }
    if ((l & 15) == 0) { hi_g[i * 4 + ht] = qi; hj_g[i * 4 + ht] = qj; }
}

// ---------------- CSR build ----------------
__global__ void k_histo(const int* __restrict__ ei, int* __restrict__ counts, int E, int N) {
    int idx = blockIdx.x * blockDim.x + threadIdx.x;
    if (idx >= E + N) return;
    int d = (idx < E) ? ei[E + idx] : (idx - E);
    atomicAdd(&counts[d], 1);
}
__global__ __launch_bounds__(256) void k_scan_partial(const int* __restrict__ counts,
                                                      int* __restrict__ bsums, int N) {
    __shared__ int sw[4];
    int s = 0;
    int base = blockIdx.x * 1024;
    for (int j = threadIdx.x; j < 1024; j += 256) {
        int idx = base + j;
        if (idx < N) s += counts[idx];
    }
#pragma unroll
    for (int m = 32; m >= 1; m >>= 1) s += __shfl_xor(s, m, 64);
    if ((threadIdx.x & 63) == 0) sw[threadIdx.x >> 6] = s;
    __syncthreads();
    if (threadIdx.x == 0) bsums[blockIdx.x] = sw[0] + sw[1] + sw[2] + sw[3];
}
__global__ __launch_bounds__(256) void k_scan_bsums(int* __restrict__ bsums, int nb,
                                                    int* __restrict__ rowptr, int N) {
    __shared__ int ss[256];
    int t = threadIdx.x;
    int v = (t < nb) ? bsums[t] : 0;
    ss[t] = v; __syncthreads();
    for (int off = 1; off < 256; off <<= 1) {
        int u = (t >= off) ? ss[t - off] : 0;
        __syncthreads();
        ss[t] += u;
        __syncthreads();
    }
    if (t < nb) bsums[t] = ss[t] - v;
    if (t == 255) rowptr[N] = ss[255];
}
__global__ __launch_bounds__(256) void k_scan_final(const int* __restrict__ counts,
                                                    const int* __restrict__ bsums,
                                                    int* __restrict__ rowptr, int N) {
    __shared__ int ss[256];
    int t = threadIdx.x;
    int base = blockIdx.x * 1024 + t * 4;
    int v0 = (base + 0 < N) ? counts[base + 0] : 0;
    int v1 = (base + 1 < N) ? counts[base + 1] : 0;
    int v2 = (base + 2 < N) ? counts[base + 2] : 0;
    int v3 = (base + 3 < N) ? counts[base + 3] : 0;
    int tot = v0 + v1 + v2 + v3;
    ss[t] = tot; __syncthreads();
    for (int off = 1; off < 256; off <<= 1) {
        int u = (t >= off) ? ss[t - off] : 0;
        __syncthreads();
        ss[t] += u;
        __syncthreads();
    }
    int excl = ss[t] - tot + bsums[blockIdx.x];
    if (base + 0 < N) rowptr[base + 0] = excl;
    if (base + 1 < N) rowptr[base + 1] = excl + v0;
    if (base + 2 < N) rowptr[base + 2] = excl + v0 + v1;
    if (base + 3 < N) rowptr[base + 3] = excl + v0 + v1 + v2;
}
__global__ void k_scatter(const int* __restrict__ ei, const int* __restrict__ rowptr,
                          int* __restrict__ cursor, int* __restrict__ srcs, int E, int N) {
    int idx = blockIdx.x * blockDim.x + threadIdx.x;
    if (idx >= E + N) return;
    int s, d;
    if (idx < E) { s = ei[idx]; d = ei[E + idx]; } else { s = d = idx - E; }
    int p = rowptr[d] + atomicAdd(&cursor[d], 1);
    srcs[p] = s;
}

// ---------------- Final stage: wave-per-node, zero barriers ----------------
__global__ __launch_bounds__(256) void k_node_final(
    const float* __restrict__ xh, const float* __restrict__ x2h,
    const float* __restrict__ lam_g, const float* __restrict__ xe,
    const float* __restrict__ hi_g, const float* __restrict__ hj_g,
    const float* __restrict__ ai_g, const float* __restrict__ aj_g,
    const int* __restrict__ rowptr, const int* __restrict__ srcs,
    const float* __restrict__ b_e, const float* __restrict__ b_h,
    const float* __restrict__ att_hf, const float* __restrict__ att_ef,
    float* __restrict__ out, int N) {
    __shared__ int   s_src_all[4][MAXD];
    __shared__ float s_d_all[4][MAXD];
    __shared__ float s_ah_all[4][MAXD * 4];
    __shared__ float s_ae_all[4][MAXD * 4];

    int wv = threadIdx.x >> 6, l = threadIdx.x & 63;
    int i = blockIdx.x * 4 + wv;
    if (i >= N) return;
    int*   s_src = s_src_all[wv];
    float* s_d   = s_d_all[wv];
    float* s_ah  = s_ah_all[wv];
    float* s_ae  = s_ae_all[wv];

    int rs = rowptr[i];
    int deg = rowptr[i + 1] - rs;
    if (deg > MAXD) deg = MAXD;
    for (int e = l; e < deg; e += 64) s_src[e] = srcs[rs + e];

    // Phase A: distances. 8 lanes/edge, 16 dims/lane, 8 edges per wave pass.
    float x2i = x2h[i];
    {
        int g = l & 7, sub = l >> 3;
        const float4* xi = (const float4*)&xh[(size_t)i * 128 + g * 16];
        float4 sx0 = xi[0], sx1 = xi[1], sx2 = xi[2], sx3 = xi[3];
        for (int p = 0; p * 8 < deg; ++p) {
            int e = p * 8 + sub;
            bool act = e < deg;
            float dot = 0.f, y2 = 0.f;
            if (act) {
                int j = s_src[e];
                const float4* rp = (const float4*)&xh[(size_t)j * 128 + g * 16];
                float4 a0 = rp[0], a1 = rp[1], a2 = rp[2], a3 = rp[3];
                y2 = x2h[j];
                dot = a0.x * sx0.x + a0.y * sx0.y + a0.z * sx0.z + a0.w * sx0.w
                    + a1.x * sx1.x + a1.y * sx1.y + a1.z * sx1.z + a1.w * sx1.w
                    + a2.x * sx2.x + a2.y * sx2.y + a2.z * sx2.z + a2.w * sx2.w
                    + a3.x * sx3.x + a3.y * sx3.y + a3.z * sx3.z + a3.w * sx3.w;
            }
            dot += __shfl_xor(dot, 1, 64);
            dot += __shfl_xor(dot, 2, 64);
            dot += __shfl_xor(dot, 4, 64);
            if (act && g == 0) {
                float xy = dot;
                float A = 1.f - 2.f * xy + y2;
                float B = 1.f - x2i;
                float den = fmaxf(1.f - 2.f * xy + x2i * y2, 1e-15f);
                float num2 = fmaxf(A * A * x2i - 2.f * A * B * xy + B * B * y2, 0.f);
                float nma = fminf(sqrtf(num2) * f_rcp(den), ART_CLIP);
                s_d[e] = f_log((1.f + nma) * f_rcp(1.f - nma));   // 2*artanh
            }
        }
    }

    // Phase B: softmax over distances (wave-local)
    float lm = -INFINITY;
    for (int e = l; e < deg; e += 64) lm = fmaxf(lm, s_d[e]);
    float md = wred_max(lm);
    float ls = 0.f;
    for (int e = l; e < deg; e += 64) { float ex = f_exp(s_d[e] - md); s_d[e] = ex; ls += ex; }
    float dinv = f_rcp(wred_sum(ls) + 1e-16f);

    // Phase C: per-edge per-head logits + two softmaxes (lane-per-edge)
    float4 hi4 = *(const float4*)&hi_g[i * 4];
    float4 ai4 = *(const float4*)&ai_g[i * 4];
    float4 mh = make_float4(-INFINITY, -INFINITY, -INFINITY, -INFINITY);
    float4 me = mh;
    for (int e = l; e < deg; e += 64) {
        int j = s_src[e];
        float ds = s_d[e] * dinv;
        float4 hj4 = *(const float4*)&hj_g[j * 4];
        float4 aj4 = *(const float4*)&aj_g[j * 4];
        float4 vh, ve;
        vh.x = leaky((hi4.x + hj4.x) * ds); vh.y = leaky((hi4.y + hj4.y) * ds);
        vh.z = leaky((hi4.z + hj4.z) * ds); vh.w = leaky((hi4.w + hj4.w) * ds);
        ve.x = leaky(ai4.x + aj4.x); ve.y = leaky(ai4.y + aj4.y);
        ve.z = leaky(ai4.z + aj4.z); ve.w = leaky(ai4.w + aj4.w);
        *(float4*)&s_ah[e * 4] = vh;
        *(float4*)&s_ae[e * 4] = ve;
        mh.x = fmaxf(mh.x, vh.x); mh.y = fmaxf(mh.y, vh.y); mh.z = fmaxf(mh.z, vh.z); mh.w = fmaxf(mh.w, vh.w);
        me.x = fmaxf(me.x, ve.x); me.y = fmaxf(me.y, ve.y); me.z = fmaxf(me.z, ve.z); me.w = fmaxf(me.w, ve.w);
    }
#pragma unroll
    for (int m = 32; m >= 1; m >>= 1) {
        mh.x = fmaxf(mh.x, __shfl_xor(mh.x, m, 64)); mh.y = fmaxf(mh.y, __shfl_xor(mh.y, m, 64));
        mh.z = fmaxf(mh.z, __shfl_xor(mh.z, m, 64)); mh.w = fmaxf(mh.w, __shfl_xor(mh.w, m, 64));
        me.x = fmaxf(me.x, __shfl_xor(me.x, m, 64)); me.y = fmaxf(me.y, __shfl_xor(me.y, m, 64));
        me.z = fmaxf(me.z, __shfl_xor(me.z, m, 64)); me.w = fmaxf(me.w, __shfl_xor(me.w, m, 64));
    }
    float4 sh = make_float4(0.f, 0.f, 0.f, 0.f), se = sh;
    for (int e = l; e < deg; e += 64) {
        float4 vh = *(float4*)&s_ah[e * 4];
        float4 ve = *(float4*)&s_ae[e * 4];
        vh.x = f_exp(vh.x - mh.x); vh.y = f_exp(vh.y - mh.y);
        vh.z = f_exp(vh.z - mh.z); vh.w = f_exp(vh.w - mh.w);
        ve.x = f_exp(ve.x - me.x); ve.y = f_exp(ve.y - me.y);
        ve.z = f_exp(ve.z - me.z); ve.w = f_exp(ve.w - me.w);
        *(float4*)&s_ah[e * 4] = vh;
        *(float4*)&s_ae[e * 4] = ve;
        sh.x += vh.x; sh.y += vh.y; sh.z += vh.z; sh.w += vh.w;
        se.x += ve.x; se.y += ve.y; se.z += ve.z; se.w += ve.w;
    }
#pragma unroll
    for (int m = 32; m >= 1; m >>= 1) {
        sh.x += __shfl_xor(sh.x, m, 64); sh.y += __shfl_xor(sh.y, m, 64);
        sh.z += __shfl_xor(sh.z, m, 64); sh.w += __shfl_xor(sh.w, m, 64);
        se.x += __shfl_xor(se.x, m, 64); se.y += __shfl_xor(se.y, m, 64);
        se.z += __shfl_xor(se.z, m, 64); se.w += __shfl_xor(se.w, m, 64);
    }
    float4 rh = make_float4(f_rcp(sh.x + 1e-16f), f_rcp(sh.y + 1e-16f),
                            f_rcp(sh.z + 1e-16f), f_rcp(sh.w + 1e-16f));
    float4 re = make_float4(f_rcp(se.x + 1e-16f), f_rcp(se.y + 1e-16f),
                            f_rcp(se.z + 1e-16f), f_rcp(se.w + 1e-16f));
    for (int e = l; e < deg; e += 64) {
        float lamj = lam_g[s_src[e]];
        float4 vh = *(float4*)&s_ah[e * 4];
        float4 ve = *(float4*)&s_ae[e * 4];
        vh.x *= rh.x * lamj; vh.y *= rh.y * lamj; vh.z *= rh.z * lamj; vh.w *= rh.w * lamj;
        ve.x *= re.x; ve.y *= re.y; ve.z *= re.z; ve.w *= re.w;
        *(float4*)&s_ah[e * 4] = vh;
        *(float4*)&s_ae[e * 4] = ve;
    }

    // Phase D: aggregation. Lane covers dims {2l, 2l+1}; in-register accumulate; unroll x2.
    int ht = l >> 4;   // head of dims 2l,2l+1
    float2 aE = make_float2(0.f, 0.f), aH = make_float2(0.f, 0.f);
    {
        int e = 0;
        for (; e + 1 < deg; e += 2) {
            int j0 = s_src[e], j1 = s_src[e + 1];
            float2 x0 = *(const float2*)&xe[(size_t)j0 * 128 + 2 * l];
            float2 h0 = *(const float2*)&xh[(size_t)j0 * 128 + 2 * l];
            float2 x1 = *(const float2*)&xe[(size_t)j1 * 128 + 2 * l];
            float2 h1 = *(const float2*)&xh[(size_t)j1 * 128 + 2 * l];
            float we0 = s_ae[e * 4 + ht], wh0 = s_ah[e * 4 + ht];
            float we1 = s_ae[(e + 1) * 4 + ht], wh1 = s_ah[(e + 1) * 4 + ht];
            aE.x += we0 * x0.x + we1 * x1.x;  aE.y += we0 * x0.y + we1 * x1.y;
            aH.x += wh0 * h0.x + wh1 * h1.x;  aH.y += wh0 * h0.y + wh1 * h1.y;
        }
        if (e < deg) {
            int j = s_src[e];
            float2 x0 = *(const float2*)&xe[(size_t)j * 128 + 2 * l];
            float2 h0 = *(const float2*)&xh[(size_t)j * 128 + 2 * l];
            float we0 = s_ae[e * 4 + ht], wh0 = s_ah[e * 4 + ht];
            aE.x += we0 * x0.x;  aE.y += we0 * x0.y;
            aH.x += wh0 * h0.x;  aH.y += wh0 * h0.y;
        }
    }

    // Phase E: epilogue — one 3-wide wave reduction, everything else analytic.
    float2 be2 = *(const float2*)&b_e[2 * l];
    float2 bh2 = *(const float2*)&b_h[2 * l];
    float2 eo = make_float2(fmaxf(aE.x + be2.x, 0.f), fmaxf(aE.y + be2.y, 0.f));
    float2 ot = make_float2(fmaxf(aH.x + bh2.x, 0.f), fmaxf(aH.y + bh2.y, 0.f));
    float n2p  = ot.x * ot.x + ot.y * ot.y;
    float ne2p = eo.x * eo.x + eo.y * eo.y;
    float dp   = ot.x * eo.x + ot.y * eo.y;
#pragma unroll
    for (int m = 32; m >= 1; m >>= 1) {
        n2p += __shfl_xor(n2p, m, 64); ne2p += __shfl_xor(ne2p, m, 64); dp += __shfl_xor(dp, m, 64);
    }
    float n2 = n2p, ne2 = ne2p, dot3 = dp;

    float n_raw = sqrtf(n2), n_c = fmaxf(n_raw, 1e-15f);
    float th = f_tanh(n_c);
    float c_h = th * f_rcp(n_c);                 // h_out = c_h * o_t
    float nh = th * (n_raw * f_rcp(n_c));
    if (nh > MAXN_BALL) { c_h *= MAXN_BALL / nh; nh = MAXN_BALL; }

    float nE_raw = sqrtf(ne2), nE_c = fmaxf(nE_raw, 1e-15f);
    float tE = f_tanh(nE_c);
    float c_e = tE * f_rcp(nE_c);                // ye = c_e * e_out
    float ny = tE * (nE_raw * f_rcp(nE_c));
    if (ny > MAXN_BALL) { c_e *= MAXN_BALL / ny; ny = MAXN_BALL; }

    float xyv = c_h * c_e * dot3;
    float x2f = nh * nh, y2f = ny * ny;
    float A = 1.f - 2.f * xyv + y2f, B = 1.f - x2f;
    float den = fmaxf(1.f - 2.f * xyv + x2f * y2f, 1e-15f);
    float num2 = fmaxf(A * A * x2f - 2.f * A * B * xyv + B * B * y2f, 0.f);
    float nma = fminf(sqrtf(num2) * f_rcp(den), ART_CLIP);
    float distf = f_log((1.f + nma) * f_rcp(1.f - nma)) * att_hf[0];
    float nyc = fmaxf(ny, 1e-15f);
    float s1 = f_tanh(distf * f_atanh(nyc)) * f_rcp(nyc);    // xe2 = s1 * ye
    float nxe2 = fabsf(s1) * ny;
    if (nxe2 > MAXN_BALL) { s1 *= MAXN_BALL / nxe2; nxe2 = MAXN_BALL; }
    float xy2 = s1 * xyv;
    float y22 = nxe2 * nxe2;
    float rden2 = f_rcp(fmaxf(1.f + 2.f * xy2 + x2f * y22, 1e-15f));
    float alpha = (1.f + 2.f * xy2 + y22) * rden2 * c_h;     // hf = alpha*o_t + beta*e_out
    float beta  = (1.f - x2f) * s1 * rden2 * c_e;
    float nf2 = alpha * alpha * n2 + 2.f * alpha * beta * dot3 + beta * beta * ne2;
    float nf = sqrtf(nf2);
    if (nf > MAXN_BALL) { float sc = MAXN_BALL / nf; alpha *= sc; beta *= sc; }
    float2 o1 = make_float2(alpha * ot.x + beta * eo.x, alpha * ot.y + beta * eo.y);
    *(float2*)&out[(size_t)i * 128 + 2 * l] = o1;

    float nhc = fmaxf(nh, 1e-15f);
    float gam = f_atanh(nhc) * f_rcp(nhc) * c_h;             // lh = gam * o_t
    float de2 = gam * gam * n2 - 2.f * gam * dot3 + ne2;
    float dg = de2 * att_ef[0] * gam;
    float2 o2 = make_float2(eo.x + dg * ot.x, eo.y + dg * ot.y);
    *(float2*)&out[(size_t)N * 128 + (size_t)i * 128 + 2 * l] = o2;
}

extern "C" void kernel_launch(void* const* d_in, const int* in_sizes, int n_in,
                              void* d_out, int out_size, void* d_ws, size_t ws_size,
                              hipStream_t stream) {
    const float* x_e      = (const float*)d_in[0];
    const float* x_h      = (const float*)d_in[1];
    const int*   ei       = (const int*)d_in[2];
    const float* W_e      = (const float*)d_in[3];
    const float* b_lin_e  = (const float*)d_in[4];
    const float* att_e    = (const float*)d_in[5];
    const float* b_e      = (const float*)d_in[6];
    const float* W_h      = (const float*)d_in[7];
    const float* b_lin_h  = (const float*)d_in[8];
    const float* att_h    = (const float*)d_in[9];
    const float* b_h      = (const float*)d_in[10];
    const float* att_hf   = (const float*)d_in[11];
    const float* att_ef   = (const float*)d_in[12];

    int N = in_sizes[0] / 128;
    int E = in_sizes[2] / 2;
    int EN = E + N;

    char* ws = (char*)d_ws;
    size_t off = 0;
    auto alloc = [&](size_t bytes) -> void* {
        void* p = ws + off;
        off = (off + bytes + 255) & ~(size_t)255;
        return p;
    };
    float* xe    = (float*)alloc((size_t)N * 128 * 4);
    float* xh    = (float*)alloc((size_t)N * 128 * 4);  // mx then xh (in place)
    float* lam   = (float*)alloc((size_t)N * 4);
    float* ai_g  = (float*)alloc((size_t)N * 4 * 4);
    float* aj_g  = (float*)alloc((size_t)N * 4 * 4);
    float* hi_g  = (float*)alloc((size_t)N * 4 * 4);
    float* hj_g  = (float*)alloc((size_t)N * 4 * 4);
    float* x2h   = (float*)alloc((size_t)N * 4);
    int*   counts= (int*)alloc((size_t)N * 4);
    int*   rowptr= (int*)alloc((size_t)(N + 1) * 4);
    int*   bsums = (int*)alloc(256 * 4);
    int*   srcs  = (int*)alloc((size_t)EN * 4);

    hipMemsetAsync(counts, 0, (size_t)N * 4, stream);

    int gblocks = (N + 31) / 32;
    dim3 ggrid(gblocks, 2);
    k_gemm2<<<ggrid, 256, 0, stream>>>(x_e, x_h, W_e, W_h, b_lin_e, xe, xh, N);

    int nblocks = (N + 3) / 4;
    k_node1<<<nblocks, 256, 0, stream>>>(xe, x_h, xh, lam, ai_g, aj_g, hi_g, hj_g, x2h,
                                         att_e, att_h, b_lin_h, N);

    int eblocks = (EN + 255) / 256;
    k_histo<<<eblocks, 256, 0, stream>>>(ei, counts, E, N);
    int nb = (N + 1023) / 1024;
    k_scan_partial<<<nb, 256, 0, stream>>>(counts, bsums, N);
    k_scan_bsums<<<1, 256, 0, stream>>>(bsums, nb, rowptr, N);
    k_scan_final<<<nb, 256, 0, stream>>>(counts, bsums, rowptr, N);
    hipMemsetAsync(counts, 0, (size_t)N * 4, stream);
    k_scatter<<<eblocks, 256, 0, stream>>>(ei, rowptr, counts, srcs, E, N);

    k_node_final<<<nblocks, 256, 0, stream>>>(xh, x2h, lam, xe, hi_g, hj_g, ai_g, aj_g,
                                              rowptr, srcs, b_e, b_h, att_hf, att_ef,
                                              (float*)d_out, N);
}

// Round 5
// 324.456 us; speedup vs baseline: 2.0249x; 1.3122x over previous
//
#include <hip/hip_runtime.h>
#include <hip/hip_fp16.h>
#include <math.h>

typedef _Float16 h2 __attribute__((ext_vector_type(2)));

#define MAXN_BALL (1.0f - 1e-5f)
#define ART_CLIP  (1.0f - 1e-7f)
#define MAXD 128   // max in-degree (incl. self-loop); Poisson(10) => P(>128) ~ 0

// ---- fast scalar math: hardware v_exp/v_log/v_rcp ----
__device__ __forceinline__ float f_rcp(float x)  { return __builtin_amdgcn_rcpf(x); }
__device__ __forceinline__ float f_exp(float x)  { return __expf(x); }
__device__ __forceinline__ float f_log(float x)  { return __logf(x); }
__device__ __forceinline__ float f_tanh(float x) {
    float ax = fabsf(x);
    float e = __expf(2.f * ax);
    float t = 1.f - 2.f * f_rcp(e + 1.f);
    return copysignf(t, x);
}
__device__ __forceinline__ float f_atanh(float x) {   // x >= 0
    x = fminf(x, ART_CLIP);
    return 0.5f * f_log((1.f + x) * f_rcp(1.f - x));
}
__device__ __forceinline__ float leaky(float x) { return x > 0.0f ? x : 0.2f * x; }

__device__ __forceinline__ float wred_sum(float v) {
#pragma unroll
    for (int m = 32; m >= 1; m >>= 1) v += __shfl_xor(v, m, 64);
    return v;
}
__device__ __forceinline__ float wred_max(float v) {
#pragma unroll
    for (int m = 32; m >= 1; m >>= 1) v = fmaxf(v, __shfl_xor(v, m, 64));
    return v;
}

union F4H8 { float4 f; h2 h[4]; };
union F2H4 { float2 f; h2 h[2]; };

// ---------------- k_prep: fused fp16-dot2 GEMMs + counts zeroing ----------------
// blockIdx.y 0: x_e @ W_e^T + b -> xe16 ; blockIdx.y 1: x_h @ W_h^T -> mx16
// blocks with blockIdx.x >= gblocks (y==0) zero the counts array.
__global__ __launch_bounds__(256) void k_prep(const float* __restrict__ X0,
                                              const float* __restrict__ X1,
                                              const float* __restrict__ W0,
                                              const float* __restrict__ W1,
                                              const float* __restrict__ bias0,
                                              h2* __restrict__ Y0,
                                              h2* __restrict__ Y1,
                                              int* __restrict__ counts,
                                              int N, int gblocks) {
    int t = threadIdx.x;
    if ((int)blockIdx.x >= gblocks) {
        if (blockIdx.y == 0) {
            int idx = ((int)blockIdx.x - gblocks) * 256 + t;
            if (idx < N) counts[idx] = 0;
        }
        return;
    }
    const float* X = blockIdx.y ? X1 : X0;
    const float* W = blockIdx.y ? W1 : W0;
    const float* bias = blockIdx.y ? nullptr : bias0;
    h2* Y = blockIdx.y ? Y1 : Y0;

    __shared__ h2 xs2[32][64];     // [row][k2]   8 KB
    __shared__ h2 wt2[64][132];    // [k2][o]    ~34 KB, stride 132 keeps b128 16B-aligned
    int r0 = blockIdx.x * 32;
#pragma unroll
    for (int it = 0; it < 4; ++it) {
        int idx = t + it * 256;          // 0..1023
        int r = idx >> 5, c4 = idx & 31;
        int gr = r0 + r;
        float4 f = (gr < N) ? *(const float4*)&X[(size_t)gr * 128 + c4 * 4]
                            : make_float4(0.f, 0.f, 0.f, 0.f);
        xs2[r][c4 * 2]     = h2{(_Float16)f.x, (_Float16)f.y};
        xs2[r][c4 * 2 + 1] = h2{(_Float16)f.z, (_Float16)f.w};
    }
#pragma unroll
    for (int it = 0; it < 16; ++it) {
        int idx = t + it * 256;          // 0..4095
        int o = idx >> 5, c4 = idx & 31;
        float4 f = *(const float4*)&W[(size_t)o * 128 + c4 * 4];
        wt2[c4 * 2][o]     = h2{(_Float16)f.x, (_Float16)f.y};
        wt2[c4 * 2 + 1][o] = h2{(_Float16)f.z, (_Float16)f.w};
    }
    __syncthreads();

    int rg = t >> 5, cg = t & 31;
    float acc[4][4] = {};
#pragma unroll 8
    for (int k2 = 0; k2 < 64; ++k2) {
        F4H8 uw; uw.f = *(const float4*)&wt2[k2][cg * 4];
        h2 x0 = xs2[rg * 4 + 0][k2];
        h2 x1 = xs2[rg * 4 + 1][k2];
        h2 x2 = xs2[rg * 4 + 2][k2];
        h2 x3 = xs2[rg * 4 + 3][k2];
#pragma unroll
        for (int c = 0; c < 4; ++c) {
            acc[0][c] = __builtin_amdgcn_fdot2(x0, uw.h[c], acc[0][c], false);
            acc[1][c] = __builtin_amdgcn_fdot2(x1, uw.h[c], acc[1][c], false);
            acc[2][c] = __builtin_amdgcn_fdot2(x2, uw.h[c], acc[2][c], false);
            acc[3][c] = __builtin_amdgcn_fdot2(x3, uw.h[c], acc[3][c], false);
        }
    }
    float4 b4 = make_float4(0.f, 0.f, 0.f, 0.f);
    if (bias) b4 = *(const float4*)&bias[cg * 4];
#pragma unroll
    for (int j = 0; j < 4; ++j) {
        int gr = r0 + rg * 4 + j;
        if (gr < N) {
            F2H4 u;
            u.h[0] = h2{(_Float16)(acc[j][0] + b4.x), (_Float16)(acc[j][1] + b4.y)};
            u.h[1] = h2{(_Float16)(acc[j][2] + b4.z), (_Float16)(acc[j][3] + b4.w)};
            *(float2*)&Y[(size_t)gr * 64 + cg * 2] = u.f;
        }
    }
}

// ---------------- k_node1_histo: per-node transforms + edge histogram ----------------
__global__ __launch_bounds__(256) void k_node1_histo(
        const h2* __restrict__ xe16, const float* __restrict__ x_h,
        const h2* __restrict__ mx16, h2* __restrict__ xh16,
        float* __restrict__ lam_g,
        float* __restrict__ ai_g, float* __restrict__ aj_g,
        float* __restrict__ hi_g, float* __restrict__ hj_g,
        float* __restrict__ x2h,
        const float* __restrict__ att_e, const float* __restrict__ att_h,
        const float* __restrict__ b_lin_h,
        const int* __restrict__ ei, int* __restrict__ counts,
        int N, int E, int nblocks) {
    int t = threadIdx.x;
    int bx = blockIdx.x;
    if (bx >= nblocks) {                       // histogram part
        int idx = (bx - nblocks) * 256 + t;
        if (idx < E + N) {
            int d = (idx < E) ? ei[E + idx] : (idx - E);
            atomicAdd(&counts[d], 1);
        }
        return;
    }
    int wv = t >> 6, l = t & 63;
    int i = bx * 4 + wv;
    if (i >= N) return;
    int ht = l >> 4, d0 = (l & 15) * 2;

    // Euclidean attention scalars from rounded xe
    h2 xeh = xe16[(size_t)i * 64 + l];
    float2 xe2 = make_float2((float)xeh.x, (float)xeh.y);
    float2 aeT = *(const float2*)&att_e[ht * 64 + d0];
    float2 aeS = *(const float2*)&att_e[ht * 64 + 32 + d0];
    float pi = xe2.x * aeT.x + xe2.y * aeT.y;
    float pj = xe2.x * aeS.x + xe2.y * aeS.y;
#pragma unroll
    for (int m = 1; m <= 8; m <<= 1) { pi += __shfl_xor(pi, m, 64); pj += __shfl_xor(pj, m, 64); }
    if ((l & 15) == 0) { ai_g[i * 4 + ht] = pi; aj_g[i * 4 + ht] = pj; }

    h2 mxh = mx16[(size_t)i * 64 + l];
    float2 mxv = make_float2((float)mxh.x, (float)mxh.y);
    float2 xv  = *(const float2*)&x_h[(size_t)i * 128 + 2 * l];
    float2 bv  = *(const float2*)&b_lin_h[2 * l];
    float nx2  = xv.x * xv.x + xv.y * xv.y;
    float nmx2 = mxv.x * mxv.x + mxv.y * mxv.y;
    float nb2  = bv.x * bv.x + bv.y * bv.y;
    float dmb  = mxv.x * bv.x + mxv.y * bv.y;
#pragma unroll
    for (int m = 32; m >= 1; m >>= 1) {
        nx2 += __shfl_xor(nx2, m, 64); nmx2 += __shfl_xor(nmx2, m, 64);
        nb2 += __shfl_xor(nb2, m, 64); dmb  += __shfl_xor(dmb, m, 64);
    }

    float nxr = sqrtf(nx2),  nxc = fmaxf(nxr, 1e-15f);
    float nmxr = sqrtf(nmx2), nmxc = fmaxf(nmxr, 1e-15f);
    float tt = f_tanh(nmxc * f_rcp(nxc) * f_atanh(nxc));
    float c_m = tt * f_rcp(nmxc);                 // mv = c_m * mx
    float nmv = tt * (nmxr * f_rcp(nmxc));
    if (nmv > MAXN_BALL) { c_m *= MAXN_BALL / nmv; nmv = MAXN_BALL; }

    float nbr = sqrtf(nb2), nbc = fmaxf(nbr, 1e-15f);
    float tb = f_tanh(nbc);
    float c_b = tb * f_rcp(nbc);                  // hb = c_b * b
    float nhb = tb * (nbr * f_rcp(nbc));
    if (nhb > MAXN_BALL) { c_b *= MAXN_BALL / nhb; nhb = MAXN_BALL; }

    float xy = c_m * c_b * dmb;
    float x2 = nmv * nmv, y2 = nhb * nhb;
    float den = fmaxf(1.f + 2.f * xy + x2 * y2, 1e-15f);
    float rden = f_rcp(den);
    float al = (1.f + 2.f * xy + y2) * c_m * rden;   // xh = al*mx + be*b
    float be = (1.f - x2) * c_b * rden;
    float nr2 = al * al * nmx2 + 2.f * al * be * dmb + be * be * nb2;
    float nrr = sqrtf(nr2);
    if (nrr > MAXN_BALL) { float sc = MAXN_BALL / nrr; al *= sc; be *= sc; }
    float2 resv = make_float2(al * mxv.x + be * bv.x, al * mxv.y + be * bv.y);
    h2 rh_ = h2{(_Float16)resv.x, (_Float16)resv.y};
    xh16[(size_t)i * 64 + l] = rh_;
    float2 rv = make_float2((float)rh_.x, (float)rh_.y);

    // norm/lam from the ROUNDED values (consistent with what node_final gathers)
    float nr2r = wred_sum(rv.x * rv.x + rv.y * rv.y);
    float nrrr = sqrtf(nr2r);
    float nnc = fmaxf(nrrr, 1e-15f);
    float lam = f_atanh(nnc) * f_rcp(nnc);
    if (l == 0) { x2h[i] = nr2r; lam_g[i] = lam; }

    float2 lxv = make_float2(lam * rv.x, lam * rv.y);
    float2 ahT = *(const float2*)&att_h[ht * 64 + d0];
    float2 ahS = *(const float2*)&att_h[ht * 64 + 32 + d0];
    float qi = lxv.x * ahT.x + lxv.y * ahT.y;
    float qj = lxv.x * ahS.x + lxv.y * ahS.y;
#pragma unroll
    for (int m = 1; m <= 8; m <<= 1) { qi += __shfl_xor(qi, m, 64); qj += __shfl_xor(qj, m, 64); }
    if ((l & 15) == 0) { hi_g[i * 4 + ht] = qi; hj_g[i * 4 + ht] = qj; }
}

// ---------------- CSR scan/scatter ----------------
__global__ __launch_bounds__(256) void k_scan_partial(const int* __restrict__ counts,
                                                      int* __restrict__ bsums, int N) {
    __shared__ int sw[4];
    int s = 0;
    int base = blockIdx.x * 1024;
    for (int j = threadIdx.x; j < 1024; j += 256) {
        int idx = base + j;
        if (idx < N) s += counts[idx];
    }
#pragma unroll
    for (int m = 32; m >= 1; m >>= 1) s += __shfl_xor(s, m, 64);
    if ((threadIdx.x & 63) == 0) sw[threadIdx.x >> 6] = s;
    __syncthreads();
    if (threadIdx.x == 0) bsums[blockIdx.x] = sw[0] + sw[1] + sw[2] + sw[3];
}
__global__ __launch_bounds__(256) void k_scan_bsums(int* __restrict__ bsums, int nb,
                                                    int* __restrict__ rowptr, int N) {
    __shared__ int ss[256];
    int t = threadIdx.x;
    int v = (t < nb) ? bsums[t] : 0;
    ss[t] = v; __syncthreads();
    for (int off = 1; off < 256; off <<= 1) {
        int u = (t >= off) ? ss[t - off] : 0;
        __syncthreads();
        ss[t] += u;
        __syncthreads();
    }
    if (t < nb) bsums[t] = ss[t] - v;
    if (t == 255) rowptr[N] = ss[255];
}
// also zeroes counts (becomes the scatter cursor)
__global__ __launch_bounds__(256) void k_scan_final(int* __restrict__ counts,
                                                    const int* __restrict__ bsums,
                                                    int* __restrict__ rowptr, int N) {
    __shared__ int ss[256];
    int t = threadIdx.x;
    int base = blockIdx.x * 1024 + t * 4;
    int v0 = (base + 0 < N) ? counts[base + 0] : 0;
    int v1 = (base + 1 < N) ? counts[base + 1] : 0;
    int v2 = (base + 2 < N) ? counts[base + 2] : 0;
    int v3 = (base + 3 < N) ? counts[base + 3] : 0;
    if (base + 0 < N) counts[base + 0] = 0;
    if (base + 1 < N) counts[base + 1] = 0;
    if (base + 2 < N) counts[base + 2] = 0;
    if (base + 3 < N) counts[base + 3] = 0;
    int tot = v0 + v1 + v2 + v3;
    ss[t] = tot; __syncthreads();
    for (int off = 1; off < 256; off <<= 1) {
        int u = (t >= off) ? ss[t - off] : 0;
        __syncthreads();
        ss[t] += u;
        __syncthreads();
    }
    int excl = ss[t] - tot + bsums[blockIdx.x];
    if (base + 0 < N) rowptr[base + 0] = excl;
    if (base + 1 < N) rowptr[base + 1] = excl + v0;
    if (base + 2 < N) rowptr[base + 2] = excl + v0 + v1;
    if (base + 3 < N) rowptr[base + 3] = excl + v0 + v1 + v2;
}
__global__ void k_scatter(const int* __restrict__ ei, const int* __restrict__ rowptr,
                          int* __restrict__ cursor, int* __restrict__ srcs, int E, int N) {
    int idx = blockIdx.x * blockDim.x + threadIdx.x;
    if (idx >= E + N) return;
    int s, d;
    if (idx < E) { s = ei[idx]; d = ei[E + idx]; } else { s = d = idx - E; }
    int p = rowptr[d] + atomicAdd(&cursor[d], 1);
    srcs[p] = s;
}

// ---------------- Final stage: wave-per-node, fp16 gathers, zero barriers ----------------
__global__ __launch_bounds__(256) void k_node_final(
    const h2* __restrict__ xh16, const float* __restrict__ x2h,
    const float* __restrict__ lam_g, const h2* __restrict__ xe16,
    const float* __restrict__ hi_g, const float* __restrict__ hj_g,
    const float* __restrict__ ai_g, const float* __restrict__ aj_g,
    const int* __restrict__ rowptr, const int* __restrict__ srcs,
    const float* __restrict__ b_e, const float* __restrict__ b_h,
    const float* __restrict__ att_hf, const float* __restrict__ att_ef,
    float* __restrict__ out, int N) {
    __shared__ int   s_src_all[4][MAXD];
    __shared__ float s_d_all[4][MAXD];
    __shared__ float s_ah_all[4][MAXD * 4];
    __shared__ float s_ae_all[4][MAXD * 4];

    int wv = threadIdx.x >> 6, l = threadIdx.x & 63;
    int i = blockIdx.x * 4 + wv;
    if (i >= N) return;
    int*   s_src = s_src_all[wv];
    float* s_d   = s_d_all[wv];
    float* s_ah  = s_ah_all[wv];
    float* s_ae  = s_ae_all[wv];

    int rs = rowptr[i];
    int deg = rowptr[i + 1] - rs;
    if (deg > MAXD) deg = MAXD;
    for (int e = l; e < deg; e += 64) s_src[e] = srcs[rs + e];

    float x2i = x2h[i];
    // Phase A: distances. 8 lanes/edge, 16 dims/lane as 8 half2 fdot2, 8 edges/pass.
    {
        int g = l & 7, sub = l >> 3;
        const h2* xi = &xh16[(size_t)i * 64 + g * 8];
        F4H8 us0, us1;
        us0.f = *(const float4*)xi;
        us1.f = *(const float4*)(xi + 4);
        for (int p = 0; p * 8 < deg; ++p) {
            int e = p * 8 + sub;
            bool act = e < deg;
            float dot = 0.f, y2 = 0.f;
            if (act) {
                int j = s_src[e];
                const h2* rp = &xh16[(size_t)j * 64 + g * 8];
                F4H8 ua, ub;
                ua.f = *(const float4*)rp;
                ub.f = *(const float4*)(rp + 4);
                y2 = x2h[j];
#pragma unroll
                for (int k = 0; k < 4; ++k) dot = __builtin_amdgcn_fdot2(ua.h[k], us0.h[k], dot, false);
#pragma unroll
                for (int k = 0; k < 4; ++k) dot = __builtin_amdgcn_fdot2(ub.h[k], us1.h[k], dot, false);
            }
            dot += __shfl_xor(dot, 1, 64);
            dot += __shfl_xor(dot, 2, 64);
            dot += __shfl_xor(dot, 4, 64);
            if (act && g == 0) {
                float xy = dot;
                float A = 1.f - 2.f * xy + y2;
                float B = 1.f - x2i;
                float den = fmaxf(1.f - 2.f * xy + x2i * y2, 1e-15f);
                float num2 = fmaxf(A * A * x2i - 2.f * A * B * xy + B * B * y2, 0.f);
                float nma = fminf(sqrtf(num2) * f_rcp(den), ART_CLIP);
                s_d[e] = f_log((1.f + nma) * f_rcp(1.f - nma));   // 2*artanh
            }
        }
    }

    // Phase B: distance softmax, register-resident (<=2 edges/lane)
    float dA = (l < deg)      ? s_d[l]      : -1e30f;
    float dB = (l + 64 < deg) ? s_d[l + 64] : -1e30f;
    float md = wred_max(fmaxf(dA, dB));
    float eA = (l < deg)      ? f_exp(dA - md) : 0.f;
    float eB = (l + 64 < deg) ? f_exp(dB - md) : 0.f;
    float dinv = f_rcp(wred_sum(eA + eB) + 1e-16f);

    // Phase C: per-edge per-head logits + two softmaxes, register slots
    float4 hi4 = *(const float4*)&hi_g[i * 4];
    float4 ai4 = *(const float4*)&ai_g[i * 4];
    float4 vh_s[2], ve_s[2];
    int j_s[2] = {0, 0};
    float4 mh = make_float4(-1e30f, -1e30f, -1e30f, -1e30f);
    float4 me = mh;
#pragma unroll
    for (int s = 0; s < 2; ++s) {
        int e = l + 64 * s;
        if (e < deg) {
            int j = s_src[e];
            j_s[s] = j;
            float ds = (s ? eB : eA) * dinv;
            float4 hj4 = *(const float4*)&hj_g[j * 4];
            float4 aj4 = *(const float4*)&aj_g[j * 4];
            float4 vh, ve;
            vh.x = leaky((hi4.x + hj4.x) * ds); vh.y = leaky((hi4.y + hj4.y) * ds);
            vh.z = leaky((hi4.z + hj4.z) * ds); vh.w = leaky((hi4.w + hj4.w) * ds);
            ve.x = leaky(ai4.x + aj4.x); ve.y = leaky(ai4.y + aj4.y);
            ve.z = leaky(ai4.z + aj4.z); ve.w = leaky(ai4.w + aj4.w);
            vh_s[s] = vh; ve_s[s] = ve;
            mh.x = fmaxf(mh.x, vh.x); mh.y = fmaxf(mh.y, vh.y);
            mh.z = fmaxf(mh.z, vh.z); mh.w = fmaxf(mh.w, vh.w);
            me.x = fmaxf(me.x, ve.x); me.y = fmaxf(me.y, ve.y);
            me.z = fmaxf(me.z, ve.z); me.w = fmaxf(me.w, ve.w);
        }
    }
#pragma unroll
    for (int m = 32; m >= 1; m >>= 1) {
        mh.x = fmaxf(mh.x, __shfl_xor(mh.x, m, 64)); mh.y = fmaxf(mh.y, __shfl_xor(mh.y, m, 64));
        mh.z = fmaxf(mh.z, __shfl_xor(mh.z, m, 64)); mh.w = fmaxf(mh.w, __shfl_xor(mh.w, m, 64));
        me.x = fmaxf(me.x, __shfl_xor(me.x, m, 64)); me.y = fmaxf(me.y, __shfl_xor(me.y, m, 64));
        me.z = fmaxf(me.z, __shfl_xor(me.z, m, 64)); me.w = fmaxf(me.w, __shfl_xor(me.w, m, 64));
    }
    float4 sh = make_float4(0.f, 0.f, 0.f, 0.f), se = sh;
#pragma unroll
    for (int s = 0; s < 2; ++s) {
        int e = l + 64 * s;
        if (e < deg) {
            float4 vh = vh_s[s], ve = ve_s[s];
            vh.x = f_exp(vh.x - mh.x); vh.y = f_exp(vh.y - mh.y);
            vh.z = f_exp(vh.z - mh.z); vh.w = f_exp(vh.w - mh.w);
            ve.x = f_exp(ve.x - me.x); ve.y = f_exp(ve.y - me.y);
            ve.z = f_exp(ve.z - me.z); ve.w = f_exp(ve.w - me.w);
            vh_s[s] = vh; ve_s[s] = ve;
            sh.x += vh.x; sh.y += vh.y; sh.z += vh.z; sh.w += vh.w;
            se.x += ve.x; se.y += ve.y; se.z += ve.z; se.w += ve.w;
        }
    }
#pragma unroll
    for (int m = 32; m >= 1; m >>= 1) {
        sh.x += __shfl_xor(sh.x, m, 64); sh.y += __shfl_xor(sh.y, m, 64);
        sh.z += __shfl_xor(sh.z, m, 64); sh.w += __shfl_xor(sh.w, m, 64);
        se.x += __shfl_xor(se.x, m, 64); se.y += __shfl_xor(se.y, m, 64);
        se.z += __shfl_xor(se.z, m, 64); se.w += __shfl_xor(se.w, m, 64);
    }
    float4 rh = make_float4(f_rcp(sh.x + 1e-16f), f_rcp(sh.y + 1e-16f),
                            f_rcp(sh.z + 1e-16f), f_rcp(sh.w + 1e-16f));
    float4 re = make_float4(f_rcp(se.x + 1e-16f), f_rcp(se.y + 1e-16f),
                            f_rcp(se.z + 1e-16f), f_rcp(se.w + 1e-16f));
#pragma unroll
    for (int s = 0; s < 2; ++s) {
        int e = l + 64 * s;
        if (e < deg) {
            float lamj = lam_g[j_s[s]];
            float4 vh = vh_s[s], ve = ve_s[s];
            vh.x *= rh.x * lamj; vh.y *= rh.y * lamj; vh.z *= rh.z * lamj; vh.w *= rh.w * lamj;
            ve.x *= re.x; ve.y *= re.y; ve.z *= re.z; ve.w *= re.w;
            *(float4*)&s_ah[e * 4] = vh;
            *(float4*)&s_ae[e * 4] = ve;
        }
    }

    // Phase D: aggregation. Lane covers dims {2l,2l+1} (one half2 per array per row).
    int ht = l >> 4;
    float2 aE = make_float2(0.f, 0.f), aH = make_float2(0.f, 0.f);
    {
        int e = 0;
        for (; e + 1 < deg; e += 2) {
            int j0 = s_src[e], j1 = s_src[e + 1];
            h2 x0 = xe16[(size_t)j0 * 64 + l];
            h2 h0 = xh16[(size_t)j0 * 64 + l];
            h2 x1 = xe16[(size_t)j1 * 64 + l];
            h2 h1 = xh16[(size_t)j1 * 64 + l];
            float we0 = s_ae[e * 4 + ht], wh0 = s_ah[e * 4 + ht];
            float we1 = s_ae[(e + 1) * 4 + ht], wh1 = s_ah[(e + 1) * 4 + ht];
            aE.x += we0 * (float)x0.x + we1 * (float)x1.x;
            aE.y += we0 * (float)x0.y + we1 * (float)x1.y;
            aH.x += wh0 * (float)h0.x + wh1 * (float)h1.x;
            aH.y += wh0 * (float)h0.y + wh1 * (float)h1.y;
        }
        if (e < deg) {
            int j = s_src[e];
            h2 x0 = xe16[(size_t)j * 64 + l];
            h2 h0 = xh16[(size_t)j * 64 + l];
            float we0 = s_ae[e * 4 + ht], wh0 = s_ah[e * 4 + ht];
            aE.x += we0 * (float)x0.x;  aE.y += we0 * (float)x0.y;
            aH.x += wh0 * (float)h0.x;  aH.y += wh0 * (float)h0.y;
        }
    }

    // Phase E: epilogue — one 3-wide wave reduction, everything else analytic.
    float2 be2 = *(const float2*)&b_e[2 * l];
    float2 bh2 = *(const float2*)&b_h[2 * l];
    float2 eo = make_float2(fmaxf(aE.x + be2.x, 0.f), fmaxf(aE.y + be2.y, 0.f));
    float2 ot = make_float2(fmaxf(aH.x + bh2.x, 0.f), fmaxf(aH.y + bh2.y, 0.f));
    float n2p  = ot.x * ot.x + ot.y * ot.y;
    float ne2p = eo.x * eo.x + eo.y * eo.y;
    float dp   = ot.x * eo.x + ot.y * eo.y;
#pragma unroll
    for (int m = 32; m >= 1; m >>= 1) {
        n2p += __shfl_xor(n2p, m, 64); ne2p += __shfl_xor(ne2p, m, 64); dp += __shfl_xor(dp, m, 64);
    }
    float n2 = n2p, ne2 = ne2p, dot3 = dp;

    float n_raw = sqrtf(n2), n_c = fmaxf(n_raw, 1e-15f);
    float th = f_tanh(n_c);
    float c_h = th * f_rcp(n_c);                 // h_out = c_h * o_t
    float nh = th * (n_raw * f_rcp(n_c));
    if (nh > MAXN_BALL) { c_h *= MAXN_BALL / nh; nh = MAXN_BALL; }

    float nE_raw = sqrtf(ne2), nE_c = fmaxf(nE_raw, 1e-15f);
    float tE = f_tanh(nE_c);
    float c_e = tE * f_rcp(nE_c);                // ye = c_e * e_out
    float ny = tE * (nE_raw * f_rcp(nE_c));
    if (ny > MAXN_BALL) { c_e *= MAXN_BALL / ny; ny = MAXN_BALL; }

    float xyv = c_h * c_e * dot3;
    float x2f = nh * nh, y2f = ny * ny;
    float A = 1.f - 2.f * xyv + y2f, B = 1.f - x2f;
    float den = fmaxf(1.f - 2.f * xyv + x2f * y2f, 1e-15f);
    float num2 = fmaxf(A * A * x2f - 2.f * A * B * xyv + B * B * y2f, 0.f);
    float nma = fminf(sqrtf(num2) * f_rcp(den), ART_CLIP);
    float distf = f_log((1.f + nma) * f_rcp(1.f - nma)) * att_hf[0];
    float nyc = fmaxf(ny, 1e-15f);
    float s1 = f_tanh(distf * f_atanh(nyc)) * f_rcp(nyc);    // xe2 = s1 * ye
    float nxe2 = fabsf(s1) * ny;
    if (nxe2 > MAXN_BALL) { s1 *= MAXN_BALL / nxe2; nxe2 = MAXN_BALL; }
    float xy2 = s1 * xyv;
    float y22 = nxe2 * nxe2;
    float rden2 = f_rcp(fmaxf(1.f + 2.f * xy2 + x2f * y22, 1e-15f));
    float alpha = (1.f + 2.f * xy2 + y22) * rden2 * c_h;     // hf = alpha*o_t + beta*e_out
    float beta  = (1.f - x2f) * s1 * rden2 * c_e;
    float nf2 = alpha * alpha * n2 + 2.f * alpha * beta * dot3 + beta * beta * ne2;
    float nf = sqrtf(nf2);
    if (nf > MAXN_BALL) { float sc = MAXN_BALL / nf; alpha *= sc; beta *= sc; }
    float2 o1 = make_float2(alpha * ot.x + beta * eo.x, alpha * ot.y + beta * eo.y);
    *(float2*)&out[(size_t)i * 128 + 2 * l] = o1;

    float nhc = fmaxf(nh, 1e-15f);
    float gam = f_atanh(nhc) * f_rcp(nhc) * c_h;             // lh = gam * o_t
    float de2 = gam * gam * n2 - 2.f * gam * dot3 + ne2;
    float dg = de2 * att_ef[0] * gam;
    float2 o2 = make_float2(eo.x + dg * ot.x, eo.y + dg * ot.y);
    *(float2*)&out[(size_t)N * 128 + (size_t)i * 128 + 2 * l] = o2;
}

extern "C" void kernel_launch(void* const* d_in, const int* in_sizes, int n_in,
                              void* d_out, int out_size, void* d_ws, size_t ws_size,
                              hipStream_t stream) {
    const float* x_e      = (const float*)d_in[0];
    const float* x_h      = (const float*)d_in[1];
    const int*   ei       = (const int*)d_in[2];
    const float* W_e      = (const float*)d_in[3];
    const float* b_lin_e  = (const float*)d_in[4];
    const float* att_e    = (const float*)d_in[5];
    const float* b_e      = (const float*)d_in[6];
    const float* W_h      = (const float*)d_in[7];
    const float* b_lin_h  = (const float*)d_in[8];
    const float* att_h    = (const float*)d_in[9];
    const float* b_h      = (const float*)d_in[10];
    const float* att_hf   = (const float*)d_in[11];
    const float* att_ef   = (const float*)d_in[12];

    int N = in_sizes[0] / 128;
    int E = in_sizes[2] / 2;
    int EN = E + N;

    char* ws = (char*)d_ws;
    size_t off = 0;
    auto alloc = [&](size_t bytes) -> void* {
        void* p = ws + off;
        off = (off + bytes + 255) & ~(size_t)255;
        return p;
    };
    h2*    xe16  = (h2*)alloc((size_t)N * 128 * 2);
    h2*    mx16  = (h2*)alloc((size_t)N * 128 * 2);
    h2*    xh16  = (h2*)alloc((size_t)N * 128 * 2);
    float* lam   = (float*)alloc((size_t)N * 4);
    float* ai_g  = (float*)alloc((size_t)N * 4 * 4);
    float* aj_g  = (float*)alloc((size_t)N * 4 * 4);
    float* hi_g  = (float*)alloc((size_t)N * 4 * 4);
    float* hj_g  = (float*)alloc((size_t)N * 4 * 4);
    float* x2h   = (float*)alloc((size_t)N * 4);
    int*   counts= (int*)alloc((size_t)N * 4);
    int*   rowptr= (int*)alloc((size_t)(N + 1) * 4);
    int*   bsums = (int*)alloc(256 * 4);
    int*   srcs  = (int*)alloc((size_t)EN * 4);

    int gblocks = (N + 31) / 32;
    int zblocks = (N + 255) / 256;
    dim3 pgrid(gblocks + zblocks, 2);
    k_prep<<<pgrid, 256, 0, stream>>>(x_e, x_h, W_e, W_h, b_lin_e,
                                      xe16, mx16, counts, N, gblocks);

    int nblocks = (N + 3) / 4;
    int eblocks = (EN + 255) / 256;
    k_node1_histo<<<nblocks + eblocks, 256, 0, stream>>>(
        xe16, x_h, mx16, xh16, lam, ai_g, aj_g, hi_g, hj_g, x2h,
        att_e, att_h, b_lin_h, ei, counts, N, E, nblocks);

    int nb = (N + 1023) / 1024;
    k_scan_partial<<<nb, 256, 0, stream>>>(counts, bsums, N);
    k_scan_bsums<<<1, 256, 0, stream>>>(bsums, nb, rowptr, N);
    k_scan_final<<<nb, 256, 0, stream>>>(counts, bsums, rowptr, N);
    k_scatter<<<eblocks, 256, 0, stream>>>(ei, rowptr, counts, srcs, E, N);

    k_node_final<<<nblocks, 256, 0, stream>>>(xh16, x2h, lam, xe16, hi_g, hj_g, ai_g, aj_g,
                                              rowptr, srcs, b_e, b_h, att_hf, att_ef,
                                              (float*)d_out, N);
}